// Round 2
// 347.736 us; speedup vs baseline: 1.0819x; 1.0819x over previous
//
#include <hip/hip_runtime.h>
#include <hip/hip_bf16.h>

// Problem constants (fixed by reference setup_inputs)
#define BB 4
#define SS 4096
#define DD 1024
#define HH 16
#define HD 64
#define MM (BB * SS)      // 16384
#define KK DD             // 1024
#define NN DD             // 1024

typedef __bf16 bf16x8 __attribute__((ext_vector_type(8)));
typedef float f32x4 __attribute__((ext_vector_type(4)));

typedef __attribute__((address_space(3))) void lds_void_t;
typedef const __attribute__((address_space(1))) void glb_void_t;

// ---------------------------------------------------------------------------
// fp32 -> bf16 conversion (vectorized)
// ---------------------------------------------------------------------------
__global__ __launch_bounds__(256)
void cvt_f32_bf16(const float* __restrict__ in, __hip_bfloat16* __restrict__ out, int n4) {
    int i = blockIdx.x * 256 + threadIdx.x;
    if (i >= n4) return;
    float4 v = ((const float4*)in)[i];
    union { __hip_bfloat16 h[4]; uint2 u; } r;
    r.h[0] = __float2bfloat16(v.x);
    r.h[1] = __float2bfloat16(v.y);
    r.h[2] = __float2bfloat16(v.z);
    r.h[3] = __float2bfloat16(v.w);
    ((uint2*)out)[i] = r.u;
}

// ---------------------------------------------------------------------------
// 256x256-tile, BK=64, 8-wave, 8-phase GEMM (m201 template, plain HIP).
//   C[M,N] = A[M,K] @ B[N,K]^T, K = 1024 (16 K-tiles of 64).
// MODE 0: N=3072 (concat Wq|Wk|Wv rows); bf16 out into concat Q|K|V buffers,
//         elu+1 fused for the Q and K thirds. grid = 768.
// MODE 1: N=1024; f32 out. grid = 256.
//
// Structure per K-tile (4 phases, 16 MFMA each):
//   ph0: ds_read all 8 B-frags + A-frags 0,1 ; stage A1(kt+1) ; MFMA i=0,1
//   ph1: ds_read A-frags 2..5                ; stage B0(kt+2) ; MFMA i=2,3
//   ph2: ds_read A-frags 6,7                 ; stage B1(kt+2) ; MFMA i=4,5
//   ph3: (no ds_reads)                       ; stage A0(kt+2) ; MFMA i=6,7
//        then s_waitcnt vmcnt(6) (vmcnt(0) at kt=14) before trailing barrier.
// vmcnt ledger (FIFO): the vmcnt(6) at end of kt retires exactly the 8 loads
// of tile kt+1; the 6 left in flight are B0/B1/A0 of tile kt+2. Every stage
// targets a region whose last reader passed a barrier:
//   B(kt) fully read in ph0 -> B(kt+2) staged ph1/ph2 safe;
//   A(kt) fully read by ph2 -> A0(kt+2) staged ph3 safe;
//   A1(kt+1) goes to the other buffer.
// LDS swizzle: logical (row,cb) stored at physical cb ^ ((row&7)<<4); applied
// as inverse swizzle on the GLOBAL source (global_load_lds dest must stay
// linear: base + lane*16), and as the same XOR on ds_read addresses.
// row&7 == lr&7 for all frag reads, so the read-side XOR is a lane constant.
// ---------------------------------------------------------------------------
#define RD_A(dst, idx)                                                                   \
    dst[0] = *(const bf16x8*)(sAb + ((idx) * 16 + lr) * 128 + ((lq * 16) ^ swz));        \
    dst[1] = *(const bf16x8*)(sAb + ((idx) * 16 + lr) * 128 + (((64) + lq * 16) ^ swz));

#define PH_WAIT                                                 \
    __builtin_amdgcn_s_barrier();                               \
    asm volatile("s_waitcnt lgkmcnt(0)" ::: "memory");          \
    __builtin_amdgcn_sched_barrier(0);

#define MFMA2(i0, i1, va, vb)                                                                         \
    __builtin_amdgcn_s_setprio(1);                                                                    \
    _Pragma("unroll")                                                                                 \
    for (int j = 0; j < 4; ++j) {                                                                     \
        acc[i0][j] = __builtin_amdgcn_mfma_f32_16x16x32_bf16(va[0], bfr[j][0], acc[i0][j], 0, 0, 0);  \
        acc[i0][j] = __builtin_amdgcn_mfma_f32_16x16x32_bf16(va[1], bfr[j][1], acc[i0][j], 0, 0, 0);  \
        acc[i1][j] = __builtin_amdgcn_mfma_f32_16x16x32_bf16(vb[0], bfr[j][0], acc[i1][j], 0, 0, 0);  \
        acc[i1][j] = __builtin_amdgcn_mfma_f32_16x16x32_bf16(vb[1], bfr[j][1], acc[i1][j], 0, 0, 0);  \
    }                                                                                                 \
    __builtin_amdgcn_s_setprio(0);

template<int MODE>
__global__ __launch_bounds__(512, 2)
void gemm256(const __hip_bfloat16* __restrict__ Ain,
             const __hip_bfloat16* __restrict__ Bin,
             __hip_bfloat16* __restrict__ Obf,
             float* __restrict__ Of32)
{
    // [buf][half][128*64] ; A-half = 128 M-rows, B-half = 128 N-rows. 128 KiB total.
    __shared__ __align__(16) __hip_bfloat16 sA[2][2][128 * 64];
    __shared__ __align__(16) __hip_bfloat16 sB[2][2][128 * 64];

    // XCD-aware bijective swizzle (nwg % 8 == 0 for both grids), m-major so
    // consecutive swizzled ids on one XCD share the B panel (L2-resident).
    const int nwg = gridDim.x;
    const int bid = blockIdx.x;
    const int s   = (bid & 7) * (nwg >> 3) + (bid >> 3);
    const int m0  = (s & 63) << 8;         // M-tile * 256
    const int n0  = (s >> 6) << 8;         // N-tile * 256

    const int t      = threadIdx.x;
    const int lane   = t & 63;
    const int w      = t >> 6;
    const int warp_m = w >> 2;             // 0..1  -> A half
    const int warp_n = w & 3;              // 0..3
    const int halfB  = warp_n >> 1;        // B half
    const int bn     = (warp_n & 1) << 6;  // 0/64 within B half
    const int lr     = lane & 15;
    const int lq     = lane >> 4;
    const int swz    = (lr & 7) << 4;      // read-side XOR (row&7 == lr&7)

    // staging constants: slot = i*512 + t ; row = slot>>3 ; row&7 == (t>>3)&7
    const int trow = t >> 3;
    const int tcb  = (((t & 7) ^ ((t >> 3) & 7)) << 4);  // inverse-swizzled src col-byte

    auto stage = [&](int ht) {             // ht = tile*4 + {0:B0,1:B1,2:A0,3:A1}
        if (ht >= 64) return;
        const int ts   = ht >> 2;
        const int kind = ht & 3;
        const int half = kind & 1;
        #pragma unroll
        for (int i = 0; i < 2; ++i) {
            const int row = i * 64 + trow;
            if (kind >= 2) {
                __builtin_amdgcn_global_load_lds(
                    (glb_void_t*)(Ain + (size_t)(m0 + half * 128 + row) * 1024 + ts * 64 + (tcb >> 1)),
                    (lds_void_t*)(&sA[ts & 1][half][(i * 512 + t) * 8]), 16, 0, 0);
            } else {
                __builtin_amdgcn_global_load_lds(
                    (glb_void_t*)(Bin + (size_t)(n0 + half * 128 + row) * 1024 + ts * 64 + (tcb >> 1)),
                    (lds_void_t*)(&sB[ts & 1][half][(i * 512 + t) * 8]), 16, 0, 0);
            }
        }
    };

    f32x4 acc[8][4];
    #pragma unroll
    for (int i = 0; i < 8; ++i)
        #pragma unroll
        for (int j = 0; j < 4; ++j)
            acc[i][j] = (f32x4){0.f, 0.f, 0.f, 0.f};

    // Prologue: tile0 (4 half-tiles) + 3 half-tiles of tile1 in flight.
    stage(0); stage(1); stage(2); stage(3);
    asm volatile("s_waitcnt vmcnt(4)" ::: "memory");
    stage(4); stage(5); stage(6);
    asm volatile("s_waitcnt vmcnt(6)" ::: "memory");
    __builtin_amdgcn_s_barrier();

    // unroll 2: folds kt&1 buffer parity per copy without 16x code explosion
    // (full unroll of this body risks compile blowup + I$ overflow).
    #pragma unroll 2
    for (int kt = 0; kt < 16; ++kt) {
        const char* sAb = (const char*)&sA[kt & 1][warp_m][0];
        const char* sBb = (const char*)&sB[kt & 1][halfB][0];
        bf16x8 bfr[4][2];
        bf16x8 a0[2], a1[2], a2[2], a3[2], a4[2], a5[2], a6[2], a7[2];

        // ---- phase 0
        #pragma unroll
        for (int j = 0; j < 4; ++j) {
            bfr[j][0] = *(const bf16x8*)(sBb + (bn + j * 16 + lr) * 128 + ((lq * 16) ^ swz));
            bfr[j][1] = *(const bf16x8*)(sBb + (bn + j * 16 + lr) * 128 + ((64 + lq * 16) ^ swz));
        }
        RD_A(a0, 0); RD_A(a1, 1);
        stage(4 * kt + 7);                  // A1(kt+1) -> other buffer
        PH_WAIT;
        MFMA2(0, 1, a0, a1);
        __builtin_amdgcn_s_barrier();

        // ---- phase 1
        RD_A(a2, 2); RD_A(a3, 3); RD_A(a4, 4); RD_A(a5, 5);
        stage(4 * kt + 8);                  // B0(kt+2) -> B(kt) fully read in ph0
        PH_WAIT;
        MFMA2(2, 3, a2, a3);
        __builtin_amdgcn_s_barrier();

        // ---- phase 2
        RD_A(a6, 6); RD_A(a7, 7);
        stage(4 * kt + 9);                  // B1(kt+2)
        PH_WAIT;
        MFMA2(4, 5, a4, a5);
        __builtin_amdgcn_s_barrier();

        // ---- phase 3
        stage(4 * kt + 10);                 // A0(kt+2) -> A(kt) fully read by ph2
        __builtin_amdgcn_s_barrier();
        MFMA2(6, 7, a6, a7);
        if (kt < 14)       { asm volatile("s_waitcnt vmcnt(6)" ::: "memory"); }
        else if (kt == 14) { asm volatile("s_waitcnt vmcnt(0)" ::: "memory"); }
        __builtin_amdgcn_s_barrier();
    }

    // Epilogue. C/D layout: col = lr, row = lq*4 + reg.
    if constexpr (MODE == 0) {
        const int wsel = n0 >> 10;                       // 0:Q 1:K 2:V (uniform per block)
        const int nb   = n0 & 1023;
        __hip_bfloat16* Op = Obf + (size_t)wsel * ((size_t)MM * KK);
        const bool doelu = (wsel < 2);
        #pragma unroll
        for (int i = 0; i < 8; ++i)
            #pragma unroll
            for (int j = 0; j < 4; ++j)
                #pragma unroll
                for (int r = 0; r < 4; ++r) {
                    const int row = m0 + warp_m * 128 + i * 16 + lq * 4 + r;
                    const int col = nb + warp_n * 64 + j * 16 + lr;
                    float v = acc[i][j][r];
                    if (doelu) v = (v > 0.f) ? v + 1.f : __expf(v);
                    Op[(size_t)row * 1024 + col] = __float2bfloat16(v);
                }
    } else {
        #pragma unroll
        for (int i = 0; i < 8; ++i)
            #pragma unroll
            for (int j = 0; j < 4; ++j)
                #pragma unroll
                for (int r = 0; r < 4; ++r) {
                    const int row = m0 + warp_m * 128 + i * 16 + lq * 4 + r;
                    const int col = n0 + warp_n * 64 + j * 16 + lr;
                    Of32[(size_t)row * 1024 + col] = acc[i][j][r];
                }
    }
}

// ---------------------------------------------------------------------------
// KV partials via MFMA (unchanged — verified)
// ---------------------------------------------------------------------------
#define KV_SPLIT 8
__global__ __launch_bounds__(256)
void kv_mfma(const __hip_bfloat16* __restrict__ Kt,
             const __hip_bfloat16* __restrict__ Vt,
             float* __restrict__ KVp)
{
    __shared__ __hip_bfloat16 sK[128 * 64];
    __shared__ __hip_bfloat16 sV[128 * 64];
    __shared__ float sRed[65 * 66];

    const int bh = blockIdx.x;
    const int b  = bh >> 4;
    const int h  = bh & 15;
    const int sp = blockIdx.y;
    const int t  = threadIdx.x;
    const int lane = t & 63;
    const int wv = t >> 6;
    const int lr = lane & 15;
    const int lq = lane >> 4;
    const int s0blk = sp * (SS / KV_SPLIT);

    const __hip_bfloat16* kbase = Kt + ((size_t)b * SS + s0blk) * DD + h * HD;
    const __hip_bfloat16* vbase = Vt + ((size_t)b * SS + s0blk) * DD + h * HD;

    f32x4 acc[4][4];
    f32x4 ksacc[4];
    #pragma unroll
    for (int i = 0; i < 4; i++) {
        ksacc[i] = (f32x4){0.f, 0.f, 0.f, 0.f};
        #pragma unroll
        for (int j = 0; j < 4; j++)
            acc[i][j] = (f32x4){0.f, 0.f, 0.f, 0.f};
    }

    bf16x8 ones;
    #pragma unroll
    for (int j = 0; j < 8; j++) ones[j] = (__bf16)1.0f;

    for (int sc = 0; sc < 4; sc++) {
        const int srow0 = sc * 128;
        #pragma unroll
        for (int i = 0; i < 4; i++) {
            int slot = i * 256 + t;
            int r = slot >> 3;
            int o = (t & 7) ^ ((r >> 3) & 3);
            size_t goff = (size_t)(srow0 + r) * DD + o * 8;
            __builtin_amdgcn_global_load_lds(
                (glb_void_t*)(kbase + goff),
                (lds_void_t*)((char*)sK + slot * 16), 16, 0, 0);
            __builtin_amdgcn_global_load_lds(
                (glb_void_t*)(vbase + goff),
                (lds_void_t*)((char*)sV + slot * 16), 16, 0, 0);
        }
        __syncthreads();

        bf16x8 ak[4], bv[4];
        #pragma unroll
        for (int i = 0; i < 4; i++) {
            #pragma unroll
            for (int j = 0; j < 8; j++) {
                int r = wv * 32 + lq * 8 + j;
                int d = i * 16 + lr;
                int idx = r * 64 + (((d >> 3) ^ lq) << 3) + (d & 7);
                ak[i][j] = ((const __bf16*)sK)[idx];
                bv[i][j] = ((const __bf16*)sV)[idx];
            }
        }
        #pragma unroll
        for (int i = 0; i < 4; i++) {
            #pragma unroll
            for (int j = 0; j < 4; j++)
                acc[i][j] = __builtin_amdgcn_mfma_f32_16x16x32_bf16(ak[i], bv[j], acc[i][j], 0, 0, 0);
            ksacc[i] = __builtin_amdgcn_mfma_f32_16x16x32_bf16(ak[i], ones, ksacc[i], 0, 0, 0);
        }
        __syncthreads();
    }

    for (int w = 0; w < 4; w++) {
        if (wv == w) {
            #pragma unroll
            for (int i = 0; i < 4; i++) {
                #pragma unroll
                for (int j = 0; j < 4; j++) {
                    float* p = &sRed[(j * 16 + lr) * 66 + i * 16 + lq * 4];
                    if (w == 0) {
                        #pragma unroll
                        for (int r = 0; r < 4; r++) p[r] = acc[i][j][r];
                    } else {
                        #pragma unroll
                        for (int r = 0; r < 4; r++) p[r] += acc[i][j][r];
                    }
                }
                if (lr == 0) {
                    float* p = &sRed[64 * 66 + i * 16 + lq * 4];
                    if (w == 0) {
                        #pragma unroll
                        for (int r = 0; r < 4; r++) p[r] = ksacc[i][r];
                    } else {
                        #pragma unroll
                        for (int r = 0; r < 4; r++) p[r] += ksacc[i][r];
                    }
                }
            }
        }
        __syncthreads();
    }

    float* outp = KVp + (size_t)(sp * 64 + bh) * (65 * 64);
    #pragma unroll
    for (int i = 0; i < 17; i++) {
        int idx = i * 256 + t;
        if (idx < 65 * 64) {
            int e = idx >> 6, d = idx & 63;
            outp[idx] = sRed[e * 66 + d];
        }
    }
}

// ---------------------------------------------------------------------------
// Reduce partials -> KVt (bf16 [bh][e][d]) + KS (f32) (unchanged)
// ---------------------------------------------------------------------------
__global__ __launch_bounds__(256)
void kv_reduce(const float* __restrict__ KVp,
               __hip_bfloat16* __restrict__ KVt,
               float* __restrict__ KS)
{
    const int bh = blockIdx.x;
    const int t  = threadIdx.x;
    #pragma unroll
    for (int i = 0; i < 16; i++) {
        int idx = i * 256 + t;
        float s = 0.f;
        #pragma unroll
        for (int sp = 0; sp < KV_SPLIT; sp++)
            s += KVp[((size_t)(sp * 64 + bh) * 65) * 64 + idx];
        KVt[(size_t)bh * 4096 + idx] = __float2bfloat16(s);
    }
    if (t < 64) {
        float s = 0.f;
        #pragma unroll
        for (int sp = 0; sp < KV_SPLIT; sp++)
            s += KVp[((size_t)(sp * 64 + bh) * 65 + 64) * 64 + t];
        KS[bh * 64 + t] = s;
    }
}

// ---------------------------------------------------------------------------
// MFMA attention apply (unchanged — verified)
// ---------------------------------------------------------------------------
__global__ __launch_bounds__(256)
void attn_mfma(const __hip_bfloat16* __restrict__ Q,
               const __hip_bfloat16* __restrict__ KVt,
               const float* __restrict__ KS,
               __hip_bfloat16* __restrict__ O)
{
    const int bh = blockIdx.x;
    const int b  = bh >> 4;
    const int h  = bh & 15;
    const int s0 = blockIdx.y * 128;
    const int t  = threadIdx.x;
    const int lane = t & 63;
    const int wv = t >> 6;

    __shared__ __align__(16) __hip_bfloat16 sQ[128][72];
    __shared__ __align__(16) __hip_bfloat16 sKVt[64][72];
    __shared__ float sKS[64];
    __shared__ float sZ[128];

    {
        const float4* kvp = (const float4*)(KVt + (size_t)bh * 4096);
        #pragma unroll
        for (int i = 0; i < 2; i++) {
            int c = i * 256 + t;
            *(float4*)(&sKVt[c >> 3][(c & 7) * 8]) = kvp[c];
        }
        if (t < 64) sKS[t] = KS[bh * 64 + t];
    }
    {
        const __hip_bfloat16* qp = Q + ((size_t)b * SS + s0) * DD + h * HD;
        int r  = t >> 1;
        int c0 = (t & 1) * 32;
        #pragma unroll
        for (int i = 0; i < 32; i += 8)
            *(float4*)(&sQ[r][c0 + i]) = *(const float4*)(qp + (size_t)r * DD + c0 + i);
    }
    __syncthreads();

    if (t < 128) {
        float z = 0.f;
        #pragma unroll
        for (int d8 = 0; d8 < 64; d8 += 8) {
            bf16x8 qv = *(const bf16x8*)(&sQ[t][d8]);
            #pragma unroll
            for (int j = 0; j < 8; j++) z += (float)qv[j] * sKS[d8 + j];
        }
        sZ[t] = 1.f / (z + 1e-6f);
    }

    const int lr = lane & 15;
    const int lq = lane >> 4;
    f32x4 acc[2][4];
    #pragma unroll
    for (int i = 0; i < 2; i++)
        #pragma unroll
        for (int j = 0; j < 4; j++)
            acc[i][j] = (f32x4){0.f, 0.f, 0.f, 0.f};

    bf16x8 af[2][2], bfv[4][2];
    #pragma unroll
    for (int ks = 0; ks < 2; ks++) {
        #pragma unroll
        for (int i = 0; i < 2; i++)
            af[i][ks] = *(const bf16x8*)(&sQ[wv * 32 + i * 16 + lr][lq * 8 + ks * 32]);
        #pragma unroll
        for (int j = 0; j < 4; j++)
            bfv[j][ks] = *(const bf16x8*)(&sKVt[j * 16 + lr][lq * 8 + ks * 32]);
    }
    #pragma unroll
    for (int i = 0; i < 2; i++)
        #pragma unroll
        for (int j = 0; j < 4; j++) {
            acc[i][j] = __builtin_amdgcn_mfma_f32_16x16x32_bf16(af[i][0], bfv[j][0], acc[i][j], 0, 0, 0);
            acc[i][j] = __builtin_amdgcn_mfma_f32_16x16x32_bf16(af[i][1], bfv[j][1], acc[i][j], 0, 0, 0);
        }
    __syncthreads();

    __hip_bfloat16* op = O + ((size_t)b * SS + s0) * DD + h * HD;
    #pragma unroll
    for (int i = 0; i < 2; i++)
        #pragma unroll
        for (int j = 0; j < 4; j++)
            #pragma unroll
            for (int r = 0; r < 4; r++) {
                int row = wv * 32 + i * 16 + lq * 4 + r;
                int col = j * 16 + lr;
                op[(size_t)row * DD + col] = __float2bfloat16(acc[i][j][r] * sZ[row]);
            }
}

// ---------------------------------------------------------------------------
// launch
// ---------------------------------------------------------------------------
extern "C" void kernel_launch(void* const* d_in, const int* in_sizes, int n_in,
                              void* d_out, int out_size, void* d_ws, size_t ws_size,
                              hipStream_t stream) {
    const float* x  = (const float*)d_in[0];
    const float* Wq = (const float*)d_in[1];
    const float* Wk = (const float*)d_in[2];
    const float* Wv = (const float*)d_in[3];
    const float* Wo = (const float*)d_in[4];
    float* out = (float*)d_out;

    char* ws = (char*)d_ws;
    const size_t XB_BYTES = (size_t)MM * KK * 2;   // 32MB
    const size_t WB_BYTES = (size_t)NN * KK * 2;   // 2MB
    __hip_bfloat16* xb  = (__hip_bfloat16*)(ws);
    __hip_bfloat16* wqb = (__hip_bfloat16*)(ws + XB_BYTES);
    __hip_bfloat16* wkb = (__hip_bfloat16*)(ws + XB_BYTES + WB_BYTES);
    __hip_bfloat16* wvb = (__hip_bfloat16*)(ws + XB_BYTES + 2 * WB_BYTES);
    __hip_bfloat16* wob = (__hip_bfloat16*)(ws + XB_BYTES + 3 * WB_BYTES);
    __hip_bfloat16* qb  = (__hip_bfloat16*)(ws + XB_BYTES + 4 * WB_BYTES);
    __hip_bfloat16* kb  = (__hip_bfloat16*)(ws + 2 * XB_BYTES + 4 * WB_BYTES);
    __hip_bfloat16* vb  = (__hip_bfloat16*)(ws + 3 * XB_BYTES + 4 * WB_BYTES);
    __hip_bfloat16* KVt = (__hip_bfloat16*)(ws + 4 * XB_BYTES + 4 * WB_BYTES);          // 512KB
    float*          KS  = (float*)(ws + 4 * XB_BYTES + 4 * WB_BYTES + 524288);          // 16KB
    // KV partials (8.3MB f32) overlay xb (dead after QKV GEMM; attn writes
    // ab=xb only after kv_reduce). Stream-ordered, safe.
    float* KVp = (float*)(ws);
    __hip_bfloat16* ab = xb;

    const int XN = MM * KK;
    const int WN = NN * KK;

    // 1. convert inputs to bf16 (wqb|wkb|wvb contiguous -> one [3072][1024] B)
    cvt_f32_bf16<<<XN / 4 / 256, 256, 0, stream>>>(x,  xb,  XN / 4);
    cvt_f32_bf16<<<WN / 4 / 256, 256, 0, stream>>>(Wq, wqb, WN / 4);
    cvt_f32_bf16<<<WN / 4 / 256, 256, 0, stream>>>(Wk, wkb, WN / 4);
    cvt_f32_bf16<<<WN / 4 / 256, 256, 0, stream>>>(Wv, wvb, WN / 4);
    cvt_f32_bf16<<<WN / 4 / 256, 256, 0, stream>>>(Wo, wob, WN / 4);

    // 2. fused QKV projection: [16384,1024] @ [3072,1024]^T, elu fused.
    //    qb|kb|vb are contiguous at stride XB_BYTES -> single output base.
    gemm256<0><<<768, 512, 0, stream>>>(xb, wqb, qb, nullptr);

    // 3. KV + k_sum partials (MFMA, no atomics), then reduce
    kv_mfma<<<dim3(BB * HH, KV_SPLIT), 256, 0, stream>>>(kb, vb, KVp);
    kv_reduce<<<BB * HH, 256, 0, stream>>>(KVp, KVt, KS);

    // 4. attention output (normalized), bf16, MFMA
    attn_mfma<<<dim3(BB * HH, SS / 128), 256, 0, stream>>>(qb, KVt, KS, ab);

    // 5. final projection -> fp32 d_out
    gemm256<1><<<256, 512, 0, stream>>>(ab, wob, nullptr, out);
}

// Round 3
// 340.993 us; speedup vs baseline: 1.1033x; 1.0198x over previous
//
#include <hip/hip_runtime.h>
#include <hip/hip_bf16.h>

// Problem constants (fixed by reference setup_inputs)
#define BB 4
#define SS 4096
#define DD 1024
#define HH 16
#define HD 64
#define MM (BB * SS)      // 16384
#define KK DD             // 1024
#define NN DD             // 1024

typedef __bf16 bf16x8 __attribute__((ext_vector_type(8)));
typedef float f32x4 __attribute__((ext_vector_type(4)));

typedef __attribute__((address_space(3))) void lds_void_t;
typedef const __attribute__((address_space(1))) void glb_void_t;

// ---------------------------------------------------------------------------
// fp32 -> bf16 conversion (vectorized)
// ---------------------------------------------------------------------------
__global__ __launch_bounds__(256)
void cvt_f32_bf16(const float* __restrict__ in, __hip_bfloat16* __restrict__ out, int n4) {
    int i = blockIdx.x * 256 + threadIdx.x;
    if (i >= n4) return;
    float4 v = ((const float4*)in)[i];
    union { __hip_bfloat16 h[4]; uint2 u; } r;
    r.h[0] = __float2bfloat16(v.x);
    r.h[1] = __float2bfloat16(v.y);
    r.h[2] = __float2bfloat16(v.z);
    r.h[3] = __float2bfloat16(v.w);
    ((uint2*)out)[i] = r.u;
}

// ---------------------------------------------------------------------------
// 256x256-tile, BK=64, 8-wave GEMM with counted-lgkmcnt clusters.
//   C[M,N] = A[M,K] @ B[N,K]^T, K = 1024 (16 K-tiles of 64).
// MODE 0: N=3072 (concat Wq|Wk|Wv); bf16 out, elu+1 fused on Q/K. grid=768.
// MODE 1: N=1024; f32 out. grid=256.
//
// Per K-tile (3 barriers, counted waits — reads overlap MFMA):
//   issue [B x8] [A01 x4] [A23 x4]  (sched_barrier-pinned groups)
//   stage A1(kt+1)
//   lgkmcnt(4)  -> B+A01 retired   ; MFMA c0 (A0,A1)
//   issue [A45 x4] [A67 x4]          (overlaps c0/c1 on LDS pipe)
//   lgkmcnt(8)  -> A23 retired     ; MFMA c1 (A2,A3)
//   BARRIER #1  -> block-wide B(kt) reads retired
//   stage B0(kt+2), B1(kt+2)
//   lgkmcnt(4)  -> A45 retired     ; MFMA c2 (A4,A5)
//   lgkmcnt(0)  -> A67 retired     ; MFMA c3 (A6,A7)
//   BARRIER #2  -> block-wide all A(kt) reads retired
//   stage A0(kt+2)
//   vmcnt(6) [vmcnt(0) at kt=14]   ; BARRIER #3 -> tile kt+1 resident
// vmcnt ledger (FIFO, 2 loads/stage): per tile issues {A1(t+1), B0,B1,A0(t+2)};
// vmcnt(6) at tile end leaves exactly B0,B1,A0(t+2) in flight -> tile t+1 landed.
// LDS swizzle: logical (row,cb) at physical cb ^ ((row&7)<<4); inverse swizzle
// applied on the GLOBAL source (global_load_lds dest must stay linear), same
// XOR on ds_read addresses (row&7 == lr&7 -> lane constant).
// ---------------------------------------------------------------------------
#define RD_A(dst, idx)                                                                   \
    dst[0] = *(const bf16x8*)(sAb + ((idx) * 16 + lr) * 128 + ((lq * 16) ^ swz));        \
    dst[1] = *(const bf16x8*)(sAb + ((idx) * 16 + lr) * 128 + (((64) + lq * 16) ^ swz));

#define MFMA2(i0, i1, va, vb)                                                                         \
    __builtin_amdgcn_s_setprio(1);                                                                    \
    _Pragma("unroll")                                                                                 \
    for (int j = 0; j < 4; ++j) {                                                                     \
        acc[i0][j] = __builtin_amdgcn_mfma_f32_16x16x32_bf16(va[0], bfr[j][0], acc[i0][j], 0, 0, 0);  \
        acc[i0][j] = __builtin_amdgcn_mfma_f32_16x16x32_bf16(va[1], bfr[j][1], acc[i0][j], 0, 0, 0);  \
        acc[i1][j] = __builtin_amdgcn_mfma_f32_16x16x32_bf16(vb[0], bfr[j][0], acc[i1][j], 0, 0, 0);  \
        acc[i1][j] = __builtin_amdgcn_mfma_f32_16x16x32_bf16(vb[1], bfr[j][1], acc[i1][j], 0, 0, 0);  \
    }                                                                                                 \
    __builtin_amdgcn_s_setprio(0);

template<int MODE>
__global__ __launch_bounds__(512, 2)
void gemm256(const __hip_bfloat16* __restrict__ Ain,
             const __hip_bfloat16* __restrict__ Bin,
             __hip_bfloat16* __restrict__ Obf,
             float* __restrict__ Of32)
{
    // [buf][half][128*64] ; A-half = 128 M-rows, B-half = 128 N-rows. 128 KiB total.
    __shared__ __align__(16) __hip_bfloat16 sA[2][2][128 * 64];
    __shared__ __align__(16) __hip_bfloat16 sB[2][2][128 * 64];

    // XCD-aware bijective swizzle (nwg % 8 == 0 for both grids), m-major so
    // consecutive swizzled ids on one XCD share the B panel (L2-resident).
    const int nwg = gridDim.x;
    const int bid = blockIdx.x;
    const int s   = (bid & 7) * (nwg >> 3) + (bid >> 3);
    const int m0  = (s & 63) << 8;         // M-tile * 256
    const int n0  = (s >> 6) << 8;         // N-tile * 256

    const int t      = threadIdx.x;
    const int lane   = t & 63;
    const int w      = t >> 6;
    const int warp_m = w >> 2;             // 0..1  -> A half
    const int warp_n = w & 3;              // 0..3
    const int halfB  = warp_n >> 1;        // B half
    const int bn     = (warp_n & 1) << 6;  // 0/64 within B half
    const int lr     = lane & 15;
    const int lq     = lane >> 4;
    const int swz    = (lr & 7) << 4;      // read-side XOR (row&7 == lr&7)

    // staging constants: slot = i*512 + t ; row = slot>>3 ; row&7 == (t>>3)&7
    const int trow = t >> 3;
    const int tcb  = (((t & 7) ^ ((t >> 3) & 7)) << 4);  // inverse-swizzled src col-byte

    auto stage = [&](int ht) {             // ht = tile*4 + {0:B0,1:B1,2:A0,3:A1}
        if (ht >= 64) return;
        const int ts   = ht >> 2;
        const int kind = ht & 3;
        const int half = kind & 1;
        #pragma unroll
        for (int i = 0; i < 2; ++i) {
            const int row = i * 64 + trow;
            if (kind >= 2) {
                __builtin_amdgcn_global_load_lds(
                    (glb_void_t*)(Ain + (size_t)(m0 + half * 128 + row) * 1024 + ts * 64 + (tcb >> 1)),
                    (lds_void_t*)(&sA[ts & 1][half][(i * 512 + t) * 8]), 16, 0, 0);
            } else {
                __builtin_amdgcn_global_load_lds(
                    (glb_void_t*)(Bin + (size_t)(n0 + half * 128 + row) * 1024 + ts * 64 + (tcb >> 1)),
                    (lds_void_t*)(&sB[ts & 1][half][(i * 512 + t) * 8]), 16, 0, 0);
            }
        }
    };

    f32x4 acc[8][4];
    #pragma unroll
    for (int i = 0; i < 8; ++i)
        #pragma unroll
        for (int j = 0; j < 4; ++j)
            acc[i][j] = (f32x4){0.f, 0.f, 0.f, 0.f};

    // Prologue: tile0 (4 half-tiles) + tile1's B0,B1,A0 in flight.
    stage(0); stage(1); stage(2); stage(3);
    stage(4); stage(5); stage(6);
    asm volatile("s_waitcnt vmcnt(6)" ::: "memory");
    __builtin_amdgcn_s_barrier();

    // unroll 2: folds kt&1 buffer parity per copy without 16x code explosion.
    #pragma unroll 2
    for (int kt = 0; kt < 16; ++kt) {
        const char* sAb = (const char*)&sA[kt & 1][warp_m][0];
        const char* sBb = (const char*)&sB[kt & 1][halfB][0];
        bf16x8 bfr[4][2];
        bf16x8 a0[2], a1[2], a2[2], a3[2], a4[2], a5[2], a6[2], a7[2];

        // group [B x8]
        #pragma unroll
        for (int j = 0; j < 4; ++j) {
            bfr[j][0] = *(const bf16x8*)(sBb + (bn + j * 16 + lr) * 128 + ((lq * 16) ^ swz));
            bfr[j][1] = *(const bf16x8*)(sBb + (bn + j * 16 + lr) * 128 + ((64 + lq * 16) ^ swz));
        }
        __builtin_amdgcn_sched_barrier(0);
        RD_A(a0, 0); RD_A(a1, 1);          // group [A01 x4]
        __builtin_amdgcn_sched_barrier(0);
        RD_A(a2, 2); RD_A(a3, 3);          // group [A23 x4]
        __builtin_amdgcn_sched_barrier(0);
        stage(4 * kt + 7);                  // A1(kt+1) -> other buffer (readers done in kt-1)

        asm volatile("s_waitcnt lgkmcnt(4)" ::: "memory");   // B + A01 retired
        __builtin_amdgcn_sched_barrier(0);
        MFMA2(0, 1, a0, a1);
        __builtin_amdgcn_sched_barrier(0);
        RD_A(a4, 4); RD_A(a5, 5);          // group [A45 x4] (overlaps c0/c1)
        __builtin_amdgcn_sched_barrier(0);
        RD_A(a6, 6); RD_A(a7, 7);          // group [A67 x4]

        asm volatile("s_waitcnt lgkmcnt(8)" ::: "memory");   // A23 retired
        __builtin_amdgcn_sched_barrier(0);
        MFMA2(2, 3, a2, a3);
        __builtin_amdgcn_s_barrier();       // #1: block-wide B(kt) reads retired
        stage(4 * kt + 8);                  // B0(kt+2)
        stage(4 * kt + 9);                  // B1(kt+2)

        asm volatile("s_waitcnt lgkmcnt(4)" ::: "memory");   // A45 retired
        __builtin_amdgcn_sched_barrier(0);
        MFMA2(4, 5, a4, a5);
        asm volatile("s_waitcnt lgkmcnt(0)" ::: "memory");   // A67 retired
        __builtin_amdgcn_sched_barrier(0);
        MFMA2(6, 7, a6, a7);
        __builtin_amdgcn_s_barrier();       // #2: block-wide all A(kt) reads retired
        stage(4 * kt + 10);                 // A0(kt+2)

        if (kt < 14)       { asm volatile("s_waitcnt vmcnt(6)" ::: "memory"); }
        else if (kt == 14) { asm volatile("s_waitcnt vmcnt(0)" ::: "memory"); }
        __builtin_amdgcn_s_barrier();       // #3: tile kt+1 resident
    }

    // Epilogue. C/D layout: col = lr, row = lq*4 + reg.
    if constexpr (MODE == 0) {
        const int wsel = n0 >> 10;                       // 0:Q 1:K 2:V (uniform per block)
        const int nb   = n0 & 1023;
        __hip_bfloat16* Op = Obf + (size_t)wsel * ((size_t)MM * KK);
        const bool doelu = (wsel < 2);
        #pragma unroll
        for (int i = 0; i < 8; ++i)
            #pragma unroll
            for (int j = 0; j < 4; ++j)
                #pragma unroll
                for (int r = 0; r < 4; ++r) {
                    const int row = m0 + warp_m * 128 + i * 16 + lq * 4 + r;
                    const int col = nb + warp_n * 64 + j * 16 + lr;
                    float v = acc[i][j][r];
                    if (doelu) v = (v > 0.f) ? v + 1.f : __expf(v);
                    Op[(size_t)row * 1024 + col] = __float2bfloat16(v);
                }
    } else {
        #pragma unroll
        for (int i = 0; i < 8; ++i)
            #pragma unroll
            for (int j = 0; j < 4; ++j)
                #pragma unroll
                for (int r = 0; r < 4; ++r) {
                    const int row = m0 + warp_m * 128 + i * 16 + lq * 4 + r;
                    const int col = n0 + warp_n * 64 + j * 16 + lr;
                    Of32[(size_t)row * 1024 + col] = acc[i][j][r];
                }
    }
}

// ---------------------------------------------------------------------------
// KV partials via MFMA (unchanged — verified)
// ---------------------------------------------------------------------------
#define KV_SPLIT 8
__global__ __launch_bounds__(256)
void kv_mfma(const __hip_bfloat16* __restrict__ Kt,
             const __hip_bfloat16* __restrict__ Vt,
             float* __restrict__ KVp)
{
    __shared__ __hip_bfloat16 sK[128 * 64];
    __shared__ __hip_bfloat16 sV[128 * 64];
    __shared__ float sRed[65 * 66];

    const int bh = blockIdx.x;
    const int b  = bh >> 4;
    const int h  = bh & 15;
    const int sp = blockIdx.y;
    const int t  = threadIdx.x;
    const int lane = t & 63;
    const int wv = t >> 6;
    const int lr = lane & 15;
    const int lq = lane >> 4;
    const int s0blk = sp * (SS / KV_SPLIT);

    const __hip_bfloat16* kbase = Kt + ((size_t)b * SS + s0blk) * DD + h * HD;
    const __hip_bfloat16* vbase = Vt + ((size_t)b * SS + s0blk) * DD + h * HD;

    f32x4 acc[4][4];
    f32x4 ksacc[4];
    #pragma unroll
    for (int i = 0; i < 4; i++) {
        ksacc[i] = (f32x4){0.f, 0.f, 0.f, 0.f};
        #pragma unroll
        for (int j = 0; j < 4; j++)
            acc[i][j] = (f32x4){0.f, 0.f, 0.f, 0.f};
    }

    bf16x8 ones;
    #pragma unroll
    for (int j = 0; j < 8; j++) ones[j] = (__bf16)1.0f;

    for (int sc = 0; sc < 4; sc++) {
        const int srow0 = sc * 128;
        #pragma unroll
        for (int i = 0; i < 4; i++) {
            int slot = i * 256 + t;
            int r = slot >> 3;
            int o = (t & 7) ^ ((r >> 3) & 3);
            size_t goff = (size_t)(srow0 + r) * DD + o * 8;
            __builtin_amdgcn_global_load_lds(
                (glb_void_t*)(kbase + goff),
                (lds_void_t*)((char*)sK + slot * 16), 16, 0, 0);
            __builtin_amdgcn_global_load_lds(
                (glb_void_t*)(vbase + goff),
                (lds_void_t*)((char*)sV + slot * 16), 16, 0, 0);
        }
        __syncthreads();

        bf16x8 ak[4], bv[4];
        #pragma unroll
        for (int i = 0; i < 4; i++) {
            #pragma unroll
            for (int j = 0; j < 8; j++) {
                int r = wv * 32 + lq * 8 + j;
                int d = i * 16 + lr;
                int idx = r * 64 + (((d >> 3) ^ lq) << 3) + (d & 7);
                ak[i][j] = ((const __bf16*)sK)[idx];
                bv[i][j] = ((const __bf16*)sV)[idx];
            }
        }
        #pragma unroll
        for (int i = 0; i < 4; i++) {
            #pragma unroll
            for (int j = 0; j < 4; j++)
                acc[i][j] = __builtin_amdgcn_mfma_f32_16x16x32_bf16(ak[i], bv[j], acc[i][j], 0, 0, 0);
            ksacc[i] = __builtin_amdgcn_mfma_f32_16x16x32_bf16(ak[i], ones, ksacc[i], 0, 0, 0);
        }
        __syncthreads();
    }

    for (int w = 0; w < 4; w++) {
        if (wv == w) {
            #pragma unroll
            for (int i = 0; i < 4; i++) {
                #pragma unroll
                for (int j = 0; j < 4; j++) {
                    float* p = &sRed[(j * 16 + lr) * 66 + i * 16 + lq * 4];
                    if (w == 0) {
                        #pragma unroll
                        for (int r = 0; r < 4; r++) p[r] = acc[i][j][r];
                    } else {
                        #pragma unroll
                        for (int r = 0; r < 4; r++) p[r] += acc[i][j][r];
                    }
                }
                if (lr == 0) {
                    float* p = &sRed[64 * 66 + i * 16 + lq * 4];
                    if (w == 0) {
                        #pragma unroll
                        for (int r = 0; r < 4; r++) p[r] = ksacc[i][r];
                    } else {
                        #pragma unroll
                        for (int r = 0; r < 4; r++) p[r] += ksacc[i][r];
                    }
                }
            }
        }
        __syncthreads();
    }

    float* outp = KVp + (size_t)(sp * 64 + bh) * (65 * 64);
    #pragma unroll
    for (int i = 0; i < 17; i++) {
        int idx = i * 256 + t;
        if (idx < 65 * 64) {
            int e = idx >> 6, d = idx & 63;
            outp[idx] = sRed[e * 66 + d];
        }
    }
}

// ---------------------------------------------------------------------------
// Reduce partials -> KVt (bf16 [bh][e][d]) + KS (f32) (unchanged)
// ---------------------------------------------------------------------------
__global__ __launch_bounds__(256)
void kv_reduce(const float* __restrict__ KVp,
               __hip_bfloat16* __restrict__ KVt,
               float* __restrict__ KS)
{
    const int bh = blockIdx.x;
    const int t  = threadIdx.x;
    #pragma unroll
    for (int i = 0; i < 16; i++) {
        int idx = i * 256 + t;
        float s = 0.f;
        #pragma unroll
        for (int sp = 0; sp < KV_SPLIT; sp++)
            s += KVp[((size_t)(sp * 64 + bh) * 65) * 64 + idx];
        KVt[(size_t)bh * 4096 + idx] = __float2bfloat16(s);
    }
    if (t < 64) {
        float s = 0.f;
        #pragma unroll
        for (int sp = 0; sp < KV_SPLIT; sp++)
            s += KVp[((size_t)(sp * 64 + bh) * 65 + 64) * 64 + t];
        KS[bh * 64 + t] = s;
    }
}

// ---------------------------------------------------------------------------
// MFMA attention apply (unchanged — verified)
// ---------------------------------------------------------------------------
__global__ __launch_bounds__(256)
void attn_mfma(const __hip_bfloat16* __restrict__ Q,
               const __hip_bfloat16* __restrict__ KVt,
               const float* __restrict__ KS,
               __hip_bfloat16* __restrict__ O)
{
    const int bh = blockIdx.x;
    const int b  = bh >> 4;
    const int h  = bh & 15;
    const int s0 = blockIdx.y * 128;
    const int t  = threadIdx.x;
    const int lane = t & 63;
    const int wv = t >> 6;

    __shared__ __align__(16) __hip_bfloat16 sQ[128][72];
    __shared__ __align__(16) __hip_bfloat16 sKVt[64][72];
    __shared__ float sKS[64];
    __shared__ float sZ[128];

    {
        const float4* kvp = (const float4*)(KVt + (size_t)bh * 4096);
        #pragma unroll
        for (int i = 0; i < 2; i++) {
            int c = i * 256 + t;
            *(float4*)(&sKVt[c >> 3][(c & 7) * 8]) = kvp[c];
        }
        if (t < 64) sKS[t] = KS[bh * 64 + t];
    }
    {
        const __hip_bfloat16* qp = Q + ((size_t)b * SS + s0) * DD + h * HD;
        int r  = t >> 1;
        int c0 = (t & 1) * 32;
        #pragma unroll
        for (int i = 0; i < 32; i += 8)
            *(float4*)(&sQ[r][c0 + i]) = *(const float4*)(qp + (size_t)r * DD + c0 + i);
    }
    __syncthreads();

    if (t < 128) {
        float z = 0.f;
        #pragma unroll
        for (int d8 = 0; d8 < 64; d8 += 8) {
            bf16x8 qv = *(const bf16x8*)(&sQ[t][d8]);
            #pragma unroll
            for (int j = 0; j < 8; j++) z += (float)qv[j] * sKS[d8 + j];
        }
        sZ[t] = 1.f / (z + 1e-6f);
    }

    const int lr = lane & 15;
    const int lq = lane >> 4;
    f32x4 acc[2][4];
    #pragma unroll
    for (int i = 0; i < 2; i++)
        #pragma unroll
        for (int j = 0; j < 4; j++)
            acc[i][j] = (f32x4){0.f, 0.f, 0.f, 0.f};

    bf16x8 af[2][2], bfv[4][2];
    #pragma unroll
    for (int ks = 0; ks < 2; ks++) {
        #pragma unroll
        for (int i = 0; i < 2; i++)
            af[i][ks] = *(const bf16x8*)(&sQ[wv * 32 + i * 16 + lr][lq * 8 + ks * 32]);
        #pragma unroll
        for (int j = 0; j < 4; j++)
            bfv[j][ks] = *(const bf16x8*)(&sKVt[j * 16 + lr][lq * 8 + ks * 32]);
    }
    #pragma unroll
    for (int i = 0; i < 2; i++)
        #pragma unroll
        for (int j = 0; j < 4; j++) {
            acc[i][j] = __builtin_amdgcn_mfma_f32_16x16x32_bf16(af[i][0], bfv[j][0], acc[i][j], 0, 0, 0);
            acc[i][j] = __builtin_amdgcn_mfma_f32_16x16x32_bf16(af[i][1], bfv[j][1], acc[i][j], 0, 0, 0);
        }
    __syncthreads();

    __hip_bfloat16* op = O + ((size_t)b * SS + s0) * DD + h * HD;
    #pragma unroll
    for (int i = 0; i < 2; i++)
        #pragma unroll
        for (int j = 0; j < 4; j++)
            #pragma unroll
            for (int r = 0; r < 4; r++) {
                int row = wv * 32 + i * 16 + lq * 4 + r;
                int col = j * 16 + lr;
                op[(size_t)row * DD + col] = __float2bfloat16(acc[i][j][r] * sZ[row]);
            }
}

// ---------------------------------------------------------------------------
// launch
// ---------------------------------------------------------------------------
extern "C" void kernel_launch(void* const* d_in, const int* in_sizes, int n_in,
                              void* d_out, int out_size, void* d_ws, size_t ws_size,
                              hipStream_t stream) {
    const float* x  = (const float*)d_in[0];
    const float* Wq = (const float*)d_in[1];
    const float* Wk = (const float*)d_in[2];
    const float* Wv = (const float*)d_in[3];
    const float* Wo = (const float*)d_in[4];
    float* out = (float*)d_out;

    char* ws = (char*)d_ws;
    const size_t XB_BYTES = (size_t)MM * KK * 2;   // 32MB
    const size_t WB_BYTES = (size_t)NN * KK * 2;   // 2MB
    __hip_bfloat16* xb  = (__hip_bfloat16*)(ws);
    __hip_bfloat16* wqb = (__hip_bfloat16*)(ws + XB_BYTES);
    __hip_bfloat16* wkb = (__hip_bfloat16*)(ws + XB_BYTES + WB_BYTES);
    __hip_bfloat16* wvb = (__hip_bfloat16*)(ws + XB_BYTES + 2 * WB_BYTES);
    __hip_bfloat16* wob = (__hip_bfloat16*)(ws + XB_BYTES + 3 * WB_BYTES);
    __hip_bfloat16* qb  = (__hip_bfloat16*)(ws + XB_BYTES + 4 * WB_BYTES);
    __hip_bfloat16* kb  = (__hip_bfloat16*)(ws + 2 * XB_BYTES + 4 * WB_BYTES);
    __hip_bfloat16* vb  = (__hip_bfloat16*)(ws + 3 * XB_BYTES + 4 * WB_BYTES);
    __hip_bfloat16* KVt = (__hip_bfloat16*)(ws + 4 * XB_BYTES + 4 * WB_BYTES);          // 512KB
    float*          KS  = (float*)(ws + 4 * XB_BYTES + 4 * WB_BYTES + 524288);          // 16KB
    // KV partials (8.3MB f32) overlay xb (dead after QKV GEMM; attn writes
    // ab=xb only after kv_reduce). Stream-ordered, safe.
    float* KVp = (float*)(ws);
    __hip_bfloat16* ab = xb;

    const int XN = MM * KK;
    const int WN = NN * KK;

    // 1. convert inputs to bf16 (wqb|wkb|wvb contiguous -> one [3072][1024] B)
    cvt_f32_bf16<<<XN / 4 / 256, 256, 0, stream>>>(x,  xb,  XN / 4);
    cvt_f32_bf16<<<WN / 4 / 256, 256, 0, stream>>>(Wq, wqb, WN / 4);
    cvt_f32_bf16<<<WN / 4 / 256, 256, 0, stream>>>(Wk, wkb, WN / 4);
    cvt_f32_bf16<<<WN / 4 / 256, 256, 0, stream>>>(Wv, wvb, WN / 4);
    cvt_f32_bf16<<<WN / 4 / 256, 256, 0, stream>>>(Wo, wob, WN / 4);

    // 2. fused QKV projection: [16384,1024] @ [3072,1024]^T, elu fused.
    //    qb|kb|vb are contiguous at stride XB_BYTES -> single output base.
    gemm256<0><<<768, 512, 0, stream>>>(xb, wqb, qb, nullptr);

    // 3. KV + k_sum partials (MFMA, no atomics), then reduce
    kv_mfma<<<dim3(BB * HH, KV_SPLIT), 256, 0, stream>>>(kb, vb, KVp);
    kv_reduce<<<BB * HH, 256, 0, stream>>>(KVp, KVt, KS);

    // 4. attention output (normalized), bf16, MFMA
    attn_mfma<<<dim3(BB * HH, SS / 128), 256, 0, stream>>>(qb, KVt, KS, ab);

    // 5. final projection -> fp32 d_out
    gemm256<1><<<256, 512, 0, stream>>>(ab, wob, nullptr, out);
}

// Round 4
// 336.607 us; speedup vs baseline: 1.1177x; 1.0130x over previous
//
#include <hip/hip_runtime.h>
#include <hip/hip_bf16.h>

// Problem constants (fixed by reference setup_inputs)
#define BB 4
#define SS 4096
#define DD 1024
#define HH 16
#define HD 64
#define MM (BB * SS)      // 16384
#define KK DD             // 1024
#define NN DD             // 1024

typedef __bf16 bf16x8 __attribute__((ext_vector_type(8)));
typedef float f32x4 __attribute__((ext_vector_type(4)));

typedef __attribute__((address_space(3))) void lds_void_t;
typedef const __attribute__((address_space(1))) void glb_void_t;

// ---------------------------------------------------------------------------
// fp32 -> bf16 conversion (vectorized)
// ---------------------------------------------------------------------------
__global__ __launch_bounds__(256)
void cvt_f32_bf16(const float* __restrict__ in, __hip_bfloat16* __restrict__ out, int n4) {
    int i = blockIdx.x * 256 + threadIdx.x;
    if (i >= n4) return;
    float4 v = ((const float4*)in)[i];
    union { __hip_bfloat16 h[4]; uint2 u; } r;
    r.h[0] = __float2bfloat16(v.x);
    r.h[1] = __float2bfloat16(v.y);
    r.h[2] = __float2bfloat16(v.z);
    r.h[3] = __float2bfloat16(v.w);
    ((uint2*)out)[i] = r.u;
}

// ---------------------------------------------------------------------------
// 256x256-tile, BK=64, 8-wave GEMM with counted-lgkmcnt clusters.
//   C[M,N] = A[M,K] @ B[N,K]^T, K = 1024 (16 K-tiles of 64).
// MODE 0: N=3072 (concat Wq|Wk|Wv); bf16 out, elu+1 fused on Q/K. grid=768.
// MODE 1: N=1024; f32 out. grid=256.
//
// Block swizzle (R4): XCD-pinned A-band. HW assigns XCD = bid%8; we map
//   mt = (bid&7)*8 + (bid>>3)&7, nt = bid>>6.
// Each XCD thus owns a FIXED 8-m-tile band of A (4 MB) for the whole
// dispatch -> A is L2-resident per XCD (was: every A read cross-XCD ->
// L3/HBM, 204 MB HBM refetch). Concurrent per-XCD working set = A 4 MB +
// B 2 MB. Bijective for both grids (768: nt in [0,12); 256: nt in [0,4)).
//
// Per K-tile (3 barriers, counted waits — reads overlap MFMA):
//   issue [B x8] [A01 x4] [A23 x4]  (sched_barrier-pinned groups)
//   stage A1(kt+1)
//   lgkmcnt(4)  -> B+A01 retired   ; MFMA c0 (A0,A1)
//   issue [A45 x4] [A67 x4]          (overlaps c0/c1 on LDS pipe)
//   lgkmcnt(8)  -> A23 retired     ; MFMA c1 (A2,A3)
//   BARRIER #1  -> block-wide B(kt) reads retired
//   stage B0(kt+2), B1(kt+2)
//   lgkmcnt(4)  -> A45 retired     ; MFMA c2 (A4,A5)
//   lgkmcnt(0)  -> A67 retired     ; MFMA c3 (A6,A7)
//   BARRIER #2  -> block-wide all A(kt) reads retired
//   stage A0(kt+2)
//   vmcnt(6) [vmcnt(0) at kt=14]   ; BARRIER #3 -> tile kt+1 resident
// vmcnt ledger (FIFO, 2 loads/stage): per tile issues {A1(t+1), B0,B1,A0(t+2)};
// vmcnt(6) at tile end leaves exactly B0,B1,A0(t+2) in flight -> tile t+1 landed.
// LDS swizzle: logical (row,cb) at physical cb ^ ((row&7)<<4); inverse swizzle
// applied on the GLOBAL source (global_load_lds dest must stay linear), same
// XOR on ds_read addresses (row&7 == lr&7 -> lane constant).
// ---------------------------------------------------------------------------
#define RD_A(dst, idx)                                                                   \
    dst[0] = *(const bf16x8*)(sAb + ((idx) * 16 + lr) * 128 + ((lq * 16) ^ swz));        \
    dst[1] = *(const bf16x8*)(sAb + ((idx) * 16 + lr) * 128 + (((64) + lq * 16) ^ swz));

#define MFMA2(i0, i1, va, vb)                                                                         \
    __builtin_amdgcn_s_setprio(1);                                                                    \
    _Pragma("unroll")                                                                                 \
    for (int j = 0; j < 4; ++j) {                                                                     \
        acc[i0][j] = __builtin_amdgcn_mfma_f32_16x16x32_bf16(va[0], bfr[j][0], acc[i0][j], 0, 0, 0);  \
        acc[i0][j] = __builtin_amdgcn_mfma_f32_16x16x32_bf16(va[1], bfr[j][1], acc[i0][j], 0, 0, 0);  \
        acc[i1][j] = __builtin_amdgcn_mfma_f32_16x16x32_bf16(vb[0], bfr[j][0], acc[i1][j], 0, 0, 0);  \
        acc[i1][j] = __builtin_amdgcn_mfma_f32_16x16x32_bf16(vb[1], bfr[j][1], acc[i1][j], 0, 0, 0);  \
    }                                                                                                 \
    __builtin_amdgcn_s_setprio(0);

template<int MODE>
__global__ __launch_bounds__(512, 2)
void gemm256(const __hip_bfloat16* __restrict__ Ain,
             const __hip_bfloat16* __restrict__ Bin,
             __hip_bfloat16* __restrict__ Obf,
             float* __restrict__ Of32)
{
    // [buf][half][128*64] ; A-half = 128 M-rows, B-half = 128 N-rows. 128 KiB total.
    __shared__ __align__(16) __hip_bfloat16 sA[2][2][128 * 64];
    __shared__ __align__(16) __hip_bfloat16 sB[2][2][128 * 64];

    // XCD-pinned A-band swizzle (see header comment).
    const int bid = blockIdx.x;
    const int mt  = ((bid & 7) << 3) | ((bid >> 3) & 7);
    const int nt  = bid >> 6;
    const int m0  = mt << 8;
    const int n0  = nt << 8;

    const int t      = threadIdx.x;
    const int lane   = t & 63;
    const int w      = t >> 6;
    const int warp_m = w >> 2;             // 0..1  -> A half
    const int warp_n = w & 3;              // 0..3
    const int halfB  = warp_n >> 1;        // B half
    const int bn     = (warp_n & 1) << 6;  // 0/64 within B half
    const int lr     = lane & 15;
    const int lq     = lane >> 4;
    const int swz    = (lr & 7) << 4;      // read-side XOR (row&7 == lr&7)

    // staging constants: slot = i*512 + t ; row = slot>>3 ; row&7 == (t>>3)&7
    const int trow = t >> 3;
    const int tcb  = (((t & 7) ^ ((t >> 3) & 7)) << 4);  // inverse-swizzled src col-byte

    auto stage = [&](int ht) {             // ht = tile*4 + {0:B0,1:B1,2:A0,3:A1}
        if (ht >= 64) return;
        const int ts   = ht >> 2;
        const int kind = ht & 3;
        const int half = kind & 1;
        #pragma unroll
        for (int i = 0; i < 2; ++i) {
            const int row = i * 64 + trow;
            if (kind >= 2) {
                __builtin_amdgcn_global_load_lds(
                    (glb_void_t*)(Ain + (size_t)(m0 + half * 128 + row) * 1024 + ts * 64 + (tcb >> 1)),
                    (lds_void_t*)(&sA[ts & 1][half][(i * 512 + t) * 8]), 16, 0, 0);
            } else {
                __builtin_amdgcn_global_load_lds(
                    (glb_void_t*)(Bin + (size_t)(n0 + half * 128 + row) * 1024 + ts * 64 + (tcb >> 1)),
                    (lds_void_t*)(&sB[ts & 1][half][(i * 512 + t) * 8]), 16, 0, 0);
            }
        }
    };

    f32x4 acc[8][4];
    #pragma unroll
    for (int i = 0; i < 8; ++i)
        #pragma unroll
        for (int j = 0; j < 4; ++j)
            acc[i][j] = (f32x4){0.f, 0.f, 0.f, 0.f};

    // Prologue: tile0 (4 half-tiles) + tile1's B0,B1,A0 in flight.
    stage(0); stage(1); stage(2); stage(3);
    stage(4); stage(5); stage(6);
    asm volatile("s_waitcnt vmcnt(6)" ::: "memory");
    __builtin_amdgcn_s_barrier();

    // unroll 2: folds kt&1 buffer parity per copy without 16x code explosion.
    #pragma unroll 2
    for (int kt = 0; kt < 16; ++kt) {
        const char* sAb = (const char*)&sA[kt & 1][warp_m][0];
        const char* sBb = (const char*)&sB[kt & 1][halfB][0];
        bf16x8 bfr[4][2];
        bf16x8 a0[2], a1[2], a2[2], a3[2], a4[2], a5[2], a6[2], a7[2];

        // group [B x8]
        #pragma unroll
        for (int j = 0; j < 4; ++j) {
            bfr[j][0] = *(const bf16x8*)(sBb + (bn + j * 16 + lr) * 128 + ((lq * 16) ^ swz));
            bfr[j][1] = *(const bf16x8*)(sBb + (bn + j * 16 + lr) * 128 + ((64 + lq * 16) ^ swz));
        }
        __builtin_amdgcn_sched_barrier(0);
        RD_A(a0, 0); RD_A(a1, 1);          // group [A01 x4]
        __builtin_amdgcn_sched_barrier(0);
        RD_A(a2, 2); RD_A(a3, 3);          // group [A23 x4]
        __builtin_amdgcn_sched_barrier(0);
        stage(4 * kt + 7);                  // A1(kt+1) -> other buffer (readers done in kt-1)

        asm volatile("s_waitcnt lgkmcnt(4)" ::: "memory");   // B + A01 retired
        __builtin_amdgcn_sched_barrier(0);
        MFMA2(0, 1, a0, a1);
        __builtin_amdgcn_sched_barrier(0);
        RD_A(a4, 4); RD_A(a5, 5);          // group [A45 x4] (overlaps c0/c1)
        __builtin_amdgcn_sched_barrier(0);
        RD_A(a6, 6); RD_A(a7, 7);          // group [A67 x4]

        asm volatile("s_waitcnt lgkmcnt(8)" ::: "memory");   // A23 retired
        __builtin_amdgcn_sched_barrier(0);
        MFMA2(2, 3, a2, a3);
        __builtin_amdgcn_s_barrier();       // #1: block-wide B(kt) reads retired
        stage(4 * kt + 8);                  // B0(kt+2)
        stage(4 * kt + 9);                  // B1(kt+2)

        asm volatile("s_waitcnt lgkmcnt(4)" ::: "memory");   // A45 retired
        __builtin_amdgcn_sched_barrier(0);
        MFMA2(4, 5, a4, a5);
        asm volatile("s_waitcnt lgkmcnt(0)" ::: "memory");   // A67 retired
        __builtin_amdgcn_sched_barrier(0);
        MFMA2(6, 7, a6, a7);
        __builtin_amdgcn_s_barrier();       // #2: block-wide all A(kt) reads retired
        stage(4 * kt + 10);                 // A0(kt+2)

        if (kt < 14)       { asm volatile("s_waitcnt vmcnt(6)" ::: "memory"); }
        else if (kt == 14) { asm volatile("s_waitcnt vmcnt(0)" ::: "memory"); }
        __builtin_amdgcn_s_barrier();       // #3: tile kt+1 resident
    }

    // Epilogue. C/D layout: col = lr, row = lq*4 + reg.
    if constexpr (MODE == 0) {
        const int wsel = n0 >> 10;                       // 0:Q 1:K 2:V (uniform per block)
        const int nb   = n0 & 1023;
        __hip_bfloat16* Op = Obf + (size_t)wsel * ((size_t)MM * KK);
        const bool doelu = (wsel < 2);
        #pragma unroll
        for (int i = 0; i < 8; ++i)
            #pragma unroll
            for (int j = 0; j < 4; ++j)
                #pragma unroll
                for (int r = 0; r < 4; ++r) {
                    const int row = m0 + warp_m * 128 + i * 16 + lq * 4 + r;
                    const int col = nb + warp_n * 64 + j * 16 + lr;
                    float v = acc[i][j][r];
                    if (doelu) v = (v > 0.f) ? v + 1.f : __expf(v);
                    Op[(size_t)row * 1024 + col] = __float2bfloat16(v);
                }
    } else {
        #pragma unroll
        for (int i = 0; i < 8; ++i)
            #pragma unroll
            for (int j = 0; j < 4; ++j)
                #pragma unroll
                for (int r = 0; r < 4; ++r) {
                    const int row = m0 + warp_m * 128 + i * 16 + lq * 4 + r;
                    const int col = n0 + warp_n * 64 + j * 16 + lr;
                    Of32[(size_t)row * 1024 + col] = acc[i][j][r];
                }
    }
}

// ---------------------------------------------------------------------------
// KV partials via MFMA (unchanged — verified)
// ---------------------------------------------------------------------------
#define KV_SPLIT 8
__global__ __launch_bounds__(256)
void kv_mfma(const __hip_bfloat16* __restrict__ Kt,
             const __hip_bfloat16* __restrict__ Vt,
             float* __restrict__ KVp)
{
    __shared__ __hip_bfloat16 sK[128 * 64];
    __shared__ __hip_bfloat16 sV[128 * 64];
    __shared__ float sRed[65 * 66];

    const int bh = blockIdx.x;
    const int b  = bh >> 4;
    const int h  = bh & 15;
    const int sp = blockIdx.y;
    const int t  = threadIdx.x;
    const int lane = t & 63;
    const int wv = t >> 6;
    const int lr = lane & 15;
    const int lq = lane >> 4;
    const int s0blk = sp * (SS / KV_SPLIT);

    const __hip_bfloat16* kbase = Kt + ((size_t)b * SS + s0blk) * DD + h * HD;
    const __hip_bfloat16* vbase = Vt + ((size_t)b * SS + s0blk) * DD + h * HD;

    f32x4 acc[4][4];
    f32x4 ksacc[4];
    #pragma unroll
    for (int i = 0; i < 4; i++) {
        ksacc[i] = (f32x4){0.f, 0.f, 0.f, 0.f};
        #pragma unroll
        for (int j = 0; j < 4; j++)
            acc[i][j] = (f32x4){0.f, 0.f, 0.f, 0.f};
    }

    bf16x8 ones;
    #pragma unroll
    for (int j = 0; j < 8; j++) ones[j] = (__bf16)1.0f;

    for (int sc = 0; sc < 4; sc++) {
        const int srow0 = sc * 128;
        #pragma unroll
        for (int i = 0; i < 4; i++) {
            int slot = i * 256 + t;
            int r = slot >> 3;
            int o = (t & 7) ^ ((r >> 3) & 3);
            size_t goff = (size_t)(srow0 + r) * DD + o * 8;
            __builtin_amdgcn_global_load_lds(
                (glb_void_t*)(kbase + goff),
                (lds_void_t*)((char*)sK + slot * 16), 16, 0, 0);
            __builtin_amdgcn_global_load_lds(
                (glb_void_t*)(vbase + goff),
                (lds_void_t*)((char*)sV + slot * 16), 16, 0, 0);
        }
        __syncthreads();

        bf16x8 ak[4], bv[4];
        #pragma unroll
        for (int i = 0; i < 4; i++) {
            #pragma unroll
            for (int j = 0; j < 8; j++) {
                int r = wv * 32 + lq * 8 + j;
                int d = i * 16 + lr;
                int idx = r * 64 + (((d >> 3) ^ lq) << 3) + (d & 7);
                ak[i][j] = ((const __bf16*)sK)[idx];
                bv[i][j] = ((const __bf16*)sV)[idx];
            }
        }
        #pragma unroll
        for (int i = 0; i < 4; i++) {
            #pragma unroll
            for (int j = 0; j < 4; j++)
                acc[i][j] = __builtin_amdgcn_mfma_f32_16x16x32_bf16(ak[i], bv[j], acc[i][j], 0, 0, 0);
            ksacc[i] = __builtin_amdgcn_mfma_f32_16x16x32_bf16(ak[i], ones, ksacc[i], 0, 0, 0);
        }
        __syncthreads();
    }

    for (int w = 0; w < 4; w++) {
        if (wv == w) {
            #pragma unroll
            for (int i = 0; i < 4; i++) {
                #pragma unroll
                for (int j = 0; j < 4; j++) {
                    float* p = &sRed[(j * 16 + lr) * 66 + i * 16 + lq * 4];
                    if (w == 0) {
                        #pragma unroll
                        for (int r = 0; r < 4; r++) p[r] = acc[i][j][r];
                    } else {
                        #pragma unroll
                        for (int r = 0; r < 4; r++) p[r] += acc[i][j][r];
                    }
                }
                if (lr == 0) {
                    float* p = &sRed[64 * 66 + i * 16 + lq * 4];
                    if (w == 0) {
                        #pragma unroll
                        for (int r = 0; r < 4; r++) p[r] = ksacc[i][r];
                    } else {
                        #pragma unroll
                        for (int r = 0; r < 4; r++) p[r] += ksacc[i][r];
                    }
                }
            }
        }
        __syncthreads();
    }

    float* outp = KVp + (size_t)(sp * 64 + bh) * (65 * 64);
    #pragma unroll
    for (int i = 0; i < 17; i++) {
        int idx = i * 256 + t;
        if (idx < 65 * 64) {
            int e = idx >> 6, d = idx & 63;
            outp[idx] = sRed[e * 66 + d];
        }
    }
}

// ---------------------------------------------------------------------------
// Reduce partials -> KVt (bf16 [bh][e][d]) + KS (f32) (unchanged)
// ---------------------------------------------------------------------------
__global__ __launch_bounds__(256)
void kv_reduce(const float* __restrict__ KVp,
               __hip_bfloat16* __restrict__ KVt,
               float* __restrict__ KS)
{
    const int bh = blockIdx.x;
    const int t  = threadIdx.x;
    #pragma unroll
    for (int i = 0; i < 16; i++) {
        int idx = i * 256 + t;
        float s = 0.f;
        #pragma unroll
        for (int sp = 0; sp < KV_SPLIT; sp++)
            s += KVp[((size_t)(sp * 64 + bh) * 65) * 64 + idx];
        KVt[(size_t)bh * 4096 + idx] = __float2bfloat16(s);
    }
    if (t < 64) {
        float s = 0.f;
        #pragma unroll
        for (int sp = 0; sp < KV_SPLIT; sp++)
            s += KVp[((size_t)(sp * 64 + bh) * 65 + 64) * 64 + t];
        KS[bh * 64 + t] = s;
    }
}

// ---------------------------------------------------------------------------
// MFMA attention apply (unchanged — verified)
// ---------------------------------------------------------------------------
__global__ __launch_bounds__(256)
void attn_mfma(const __hip_bfloat16* __restrict__ Q,
               const __hip_bfloat16* __restrict__ KVt,
               const float* __restrict__ KS,
               __hip_bfloat16* __restrict__ O)
{
    const int bh = blockIdx.x;
    const int b  = bh >> 4;
    const int h  = bh & 15;
    const int s0 = blockIdx.y * 128;
    const int t  = threadIdx.x;
    const int lane = t & 63;
    const int wv = t >> 6;

    __shared__ __align__(16) __hip_bfloat16 sQ[128][72];
    __shared__ __align__(16) __hip_bfloat16 sKVt[64][72];
    __shared__ float sKS[64];
    __shared__ float sZ[128];

    {
        const float4* kvp = (const float4*)(KVt + (size_t)bh * 4096);
        #pragma unroll
        for (int i = 0; i < 2; i++) {
            int c = i * 256 + t;
            *(float4*)(&sKVt[c >> 3][(c & 7) * 8]) = kvp[c];
        }
        if (t < 64) sKS[t] = KS[bh * 64 + t];
    }
    {
        const __hip_bfloat16* qp = Q + ((size_t)b * SS + s0) * DD + h * HD;
        int r  = t >> 1;
        int c0 = (t & 1) * 32;
        #pragma unroll
        for (int i = 0; i < 32; i += 8)
            *(float4*)(&sQ[r][c0 + i]) = *(const float4*)(qp + (size_t)r * DD + c0 + i);
    }
    __syncthreads();

    if (t < 128) {
        float z = 0.f;
        #pragma unroll
        for (int d8 = 0; d8 < 64; d8 += 8) {
            bf16x8 qv = *(const bf16x8*)(&sQ[t][d8]);
            #pragma unroll
            for (int j = 0; j < 8; j++) z += (float)qv[j] * sKS[d8 + j];
        }
        sZ[t] = 1.f / (z + 1e-6f);
    }

    const int lr = lane & 15;
    const int lq = lane >> 4;
    f32x4 acc[2][4];
    #pragma unroll
    for (int i = 0; i < 2; i++)
        #pragma unroll
        for (int j = 0; j < 4; j++)
            acc[i][j] = (f32x4){0.f, 0.f, 0.f, 0.f};

    bf16x8 af[2][2], bfv[4][2];
    #pragma unroll
    for (int ks = 0; ks < 2; ks++) {
        #pragma unroll
        for (int i = 0; i < 2; i++)
            af[i][ks] = *(const bf16x8*)(&sQ[wv * 32 + i * 16 + lr][lq * 8 + ks * 32]);
        #pragma unroll
        for (int j = 0; j < 4; j++)
            bfv[j][ks] = *(const bf16x8*)(&sKVt[j * 16 + lr][lq * 8 + ks * 32]);
    }
    #pragma unroll
    for (int i = 0; i < 2; i++)
        #pragma unroll
        for (int j = 0; j < 4; j++) {
            acc[i][j] = __builtin_amdgcn_mfma_f32_16x16x32_bf16(af[i][0], bfv[j][0], acc[i][j], 0, 0, 0);
            acc[i][j] = __builtin_amdgcn_mfma_f32_16x16x32_bf16(af[i][1], bfv[j][1], acc[i][j], 0, 0, 0);
        }
    __syncthreads();

    __hip_bfloat16* op = O + ((size_t)b * SS + s0) * DD + h * HD;
    #pragma unroll
    for (int i = 0; i < 2; i++)
        #pragma unroll
        for (int j = 0; j < 4; j++)
            #pragma unroll
            for (int r = 0; r < 4; r++) {
                int row = wv * 32 + i * 16 + lq * 4 + r;
                int col = j * 16 + lr;
                op[(size_t)row * DD + col] = __float2bfloat16(acc[i][j][r] * sZ[row]);
            }
}

// ---------------------------------------------------------------------------
// launch
// ---------------------------------------------------------------------------
extern "C" void kernel_launch(void* const* d_in, const int* in_sizes, int n_in,
                              void* d_out, int out_size, void* d_ws, size_t ws_size,
                              hipStream_t stream) {
    const float* x  = (const float*)d_in[0];
    const float* Wq = (const float*)d_in[1];
    const float* Wk = (const float*)d_in[2];
    const float* Wv = (const float*)d_in[3];
    const float* Wo = (const float*)d_in[4];
    float* out = (float*)d_out;

    char* ws = (char*)d_ws;
    const size_t XB_BYTES = (size_t)MM * KK * 2;   // 32MB
    const size_t WB_BYTES = (size_t)NN * KK * 2;   // 2MB
    __hip_bfloat16* xb  = (__hip_bfloat16*)(ws);
    __hip_bfloat16* wqb = (__hip_bfloat16*)(ws + XB_BYTES);
    __hip_bfloat16* wkb = (__hip_bfloat16*)(ws + XB_BYTES + WB_BYTES);
    __hip_bfloat16* wvb = (__hip_bfloat16*)(ws + XB_BYTES + 2 * WB_BYTES);
    __hip_bfloat16* wob = (__hip_bfloat16*)(ws + XB_BYTES + 3 * WB_BYTES);
    __hip_bfloat16* qb  = (__hip_bfloat16*)(ws + XB_BYTES + 4 * WB_BYTES);
    __hip_bfloat16* kb  = (__hip_bfloat16*)(ws + 2 * XB_BYTES + 4 * WB_BYTES);
    __hip_bfloat16* vb  = (__hip_bfloat16*)(ws + 3 * XB_BYTES + 4 * WB_BYTES);
    __hip_bfloat16* KVt = (__hip_bfloat16*)(ws + 4 * XB_BYTES + 4 * WB_BYTES);          // 512KB
    float*          KS  = (float*)(ws + 4 * XB_BYTES + 4 * WB_BYTES + 524288);          // 16KB
    // KV partials (8.3MB f32) overlay xb (dead after QKV GEMM; attn writes
    // ab=xb only after kv_reduce). Stream-ordered, safe.
    float* KVp = (float*)(ws);
    __hip_bfloat16* ab = xb;

    const int XN = MM * KK;
    const int WN = NN * KK;

    // 1. convert inputs to bf16 (wqb|wkb|wvb contiguous -> one [3072][1024] B)
    cvt_f32_bf16<<<XN / 4 / 256, 256, 0, stream>>>(x,  xb,  XN / 4);
    cvt_f32_bf16<<<WN / 4 / 256, 256, 0, stream>>>(Wq, wqb, WN / 4);
    cvt_f32_bf16<<<WN / 4 / 256, 256, 0, stream>>>(Wk, wkb, WN / 4);
    cvt_f32_bf16<<<WN / 4 / 256, 256, 0, stream>>>(Wv, wvb, WN / 4);
    cvt_f32_bf16<<<WN / 4 / 256, 256, 0, stream>>>(Wo, wob, WN / 4);

    // 2. fused QKV projection: [16384,1024] @ [3072,1024]^T, elu fused.
    //    qb|kb|vb are contiguous at stride XB_BYTES -> single output base.
    gemm256<0><<<768, 512, 0, stream>>>(xb, wqb, qb, nullptr);

    // 3. KV + k_sum partials (MFMA, no atomics), then reduce
    kv_mfma<<<dim3(BB * HH, KV_SPLIT), 256, 0, stream>>>(kb, vb, KVp);
    kv_reduce<<<BB * HH, 256, 0, stream>>>(KVp, KVt, KS);

    // 4. attention output (normalized), bf16, MFMA
    attn_mfma<<<dim3(BB * HH, SS / 128), 256, 0, stream>>>(qb, KVt, KS, ab);

    // 5. final projection -> fp32 d_out
    gemm256<1><<<256, 512, 0, stream>>>(ab, wob, nullptr, out);
}

// Round 6
// 336.057 us; speedup vs baseline: 1.1195x; 1.0016x over previous
//
#include <hip/hip_runtime.h>
#include <hip/hip_bf16.h>

// Problem constants (fixed by reference setup_inputs)
#define BB 4
#define SS 4096
#define DD 1024
#define HH 16
#define HD 64
#define MM (BB * SS)      // 16384
#define KK DD             // 1024
#define NN DD             // 1024

typedef __bf16 bf16x8 __attribute__((ext_vector_type(8)));
typedef float f32x4 __attribute__((ext_vector_type(4)));

typedef __attribute__((address_space(3))) void lds_void_t;
typedef const __attribute__((address_space(1))) void glb_void_t;

// ---------------------------------------------------------------------------
// fp32 -> bf16 conversion (vectorized)
// ---------------------------------------------------------------------------
__global__ __launch_bounds__(256)
void cvt_f32_bf16(const float* __restrict__ in, __hip_bfloat16* __restrict__ out, int n4) {
    int i = blockIdx.x * 256 + threadIdx.x;
    if (i >= n4) return;
    float4 v = ((const float4*)in)[i];
    union { __hip_bfloat16 h[4]; uint2 u; } r;
    r.h[0] = __float2bfloat16(v.x);
    r.h[1] = __float2bfloat16(v.y);
    r.h[2] = __float2bfloat16(v.z);
    r.h[3] = __float2bfloat16(v.w);
    ((uint2*)out)[i] = r.u;
}

// ---------------------------------------------------------------------------
// 256x256-tile, BK=64, 8-wave GEMM with counted-lgkmcnt clusters.
//   C[M,N] = A[M,K] @ B[N,K]^T, K = 1024 (16 K-tiles of 64).
// MODE 0: N=3072 (concat Wq|Wk|Wv). Q third: bf16 row-major + elu+1.
//         K third: elu+1, TRANSPOSED [bh][hd][s] packed uint2 stores.
//         V third: TRANSPOSED [bh][hd][s] packed uint2 stores.
//         grid = 768.
// MODE 1: N=1024; f32 out row-major. grid = 256.
//
// Block swizzle: XCD-pinned A-band (HW XCD = bid%8):
//   mt = (bid&7)*8 + (bid>>3)&7, nt = bid>>6  -> each XCD owns a fixed
// 8-m-tile band of A (4 MB, L2-resident). Verified R4: FETCH 204->75 MB.
//
// Per K-tile (3 barriers, counted waits — reads overlap MFMA): see R3 header.
// vmcnt ledger (FIFO, 2 loads/stage): per tile issues {A1(t+1), B0,B1,A0(t+2)};
// vmcnt(6) at tile end leaves exactly B0,B1,A0(t+2) in flight.
// LDS swizzle: logical (row,cb) at physical cb ^ ((row&7)<<4); inverse swizzle
// on the GLOBAL source (global_load_lds dest stays linear), same XOR on
// ds_read addresses (row&7 == lr&7 -> lane constant). 0 bank conflicts (R2+).
// ---------------------------------------------------------------------------
#define RD_A(dst, idx)                                                                   \
    dst[0] = *(const bf16x8*)(sAb + ((idx) * 16 + lr) * 128 + ((lq * 16) ^ swz));        \
    dst[1] = *(const bf16x8*)(sAb + ((idx) * 16 + lr) * 128 + (((64) + lq * 16) ^ swz));

#define MFMA2(i0, i1, va, vb)                                                                         \
    __builtin_amdgcn_s_setprio(1);                                                                    \
    _Pragma("unroll")                                                                                 \
    for (int j = 0; j < 4; ++j) {                                                                     \
        acc[i0][j] = __builtin_amdgcn_mfma_f32_16x16x32_bf16(va[0], bfr[j][0], acc[i0][j], 0, 0, 0);  \
        acc[i0][j] = __builtin_amdgcn_mfma_f32_16x16x32_bf16(va[1], bfr[j][1], acc[i0][j], 0, 0, 0);  \
        acc[i1][j] = __builtin_amdgcn_mfma_f32_16x16x32_bf16(vb[0], bfr[j][0], acc[i1][j], 0, 0, 0);  \
        acc[i1][j] = __builtin_amdgcn_mfma_f32_16x16x32_bf16(vb[1], bfr[j][1], acc[i1][j], 0, 0, 0);  \
    }                                                                                                 \
    __builtin_amdgcn_s_setprio(0);

template<int MODE>
__global__ __launch_bounds__(512, 2)
void gemm256(const __hip_bfloat16* __restrict__ Ain,
             const __hip_bfloat16* __restrict__ Bin,
             __hip_bfloat16* __restrict__ Obf,
             float* __restrict__ Of32)
{
    __shared__ __align__(16) __hip_bfloat16 sA[2][2][128 * 64];
    __shared__ __align__(16) __hip_bfloat16 sB[2][2][128 * 64];

    // XCD-pinned A-band swizzle.
    const int bid = blockIdx.x;
    const int mt  = ((bid & 7) << 3) | ((bid >> 3) & 7);
    const int nt  = bid >> 6;
    const int m0  = mt << 8;
    const int n0  = nt << 8;

    const int t      = threadIdx.x;
    const int lane   = t & 63;
    const int w      = t >> 6;
    const int warp_m = w >> 2;             // 0..1  -> A half
    const int warp_n = w & 3;              // 0..3
    const int halfB  = warp_n >> 1;        // B half
    const int bn     = (warp_n & 1) << 6;  // 0/64 within B half
    const int lr     = lane & 15;
    const int lq     = lane >> 4;
    const int swz    = (lr & 7) << 4;      // read-side XOR (row&7 == lr&7)

    const int trow = t >> 3;
    const int tcb  = (((t & 7) ^ ((t >> 3) & 7)) << 4);  // inverse-swizzled src col-byte

    auto stage = [&](int ht) {             // ht = tile*4 + {0:B0,1:B1,2:A0,3:A1}
        if (ht >= 64) return;
        const int ts   = ht >> 2;
        const int kind = ht & 3;
        const int half = kind & 1;
        #pragma unroll
        for (int i = 0; i < 2; ++i) {
            const int row = i * 64 + trow;
            if (kind >= 2) {
                __builtin_amdgcn_global_load_lds(
                    (glb_void_t*)(Ain + (size_t)(m0 + half * 128 + row) * 1024 + ts * 64 + (tcb >> 1)),
                    (lds_void_t*)(&sA[ts & 1][half][(i * 512 + t) * 8]), 16, 0, 0);
            } else {
                __builtin_amdgcn_global_load_lds(
                    (glb_void_t*)(Bin + (size_t)(n0 + half * 128 + row) * 1024 + ts * 64 + (tcb >> 1)),
                    (lds_void_t*)(&sB[ts & 1][half][(i * 512 + t) * 8]), 16, 0, 0);
            }
        }
    };

    f32x4 acc[8][4];
    #pragma unroll
    for (int i = 0; i < 8; ++i)
        #pragma unroll
        for (int j = 0; j < 4; ++j)
            acc[i][j] = (f32x4){0.f, 0.f, 0.f, 0.f};

    // Prologue: tile0 (4 half-tiles) + tile1's B0,B1,A0 in flight.
    stage(0); stage(1); stage(2); stage(3);
    stage(4); stage(5); stage(6);
    asm volatile("s_waitcnt vmcnt(6)" ::: "memory");
    __builtin_amdgcn_s_barrier();

    #pragma unroll 2
    for (int kt = 0; kt < 16; ++kt) {
        const char* sAb = (const char*)&sA[kt & 1][warp_m][0];
        const char* sBb = (const char*)&sB[kt & 1][halfB][0];
        bf16x8 bfr[4][2];
        bf16x8 a0[2], a1[2], a2[2], a3[2], a4[2], a5[2], a6[2], a7[2];

        // group [B x8]
        #pragma unroll
        for (int j = 0; j < 4; ++j) {
            bfr[j][0] = *(const bf16x8*)(sBb + (bn + j * 16 + lr) * 128 + ((lq * 16) ^ swz));
            bfr[j][1] = *(const bf16x8*)(sBb + (bn + j * 16 + lr) * 128 + ((64 + lq * 16) ^ swz));
        }
        __builtin_amdgcn_sched_barrier(0);
        RD_A(a0, 0); RD_A(a1, 1);          // group [A01 x4]
        __builtin_amdgcn_sched_barrier(0);
        RD_A(a2, 2); RD_A(a3, 3);          // group [A23 x4]
        __builtin_amdgcn_sched_barrier(0);
        stage(4 * kt + 7);                  // A1(kt+1) -> other buffer

        asm volatile("s_waitcnt lgkmcnt(4)" ::: "memory");   // B + A01 retired
        __builtin_amdgcn_sched_barrier(0);
        MFMA2(0, 1, a0, a1);
        __builtin_amdgcn_sched_barrier(0);
        RD_A(a4, 4); RD_A(a5, 5);          // group [A45 x4]
        __builtin_amdgcn_sched_barrier(0);
        RD_A(a6, 6); RD_A(a7, 7);          // group [A67 x4]

        asm volatile("s_waitcnt lgkmcnt(8)" ::: "memory");   // A23 retired
        __builtin_amdgcn_sched_barrier(0);
        MFMA2(2, 3, a2, a3);
        __builtin_amdgcn_s_barrier();       // #1: block-wide B(kt) reads retired
        stage(4 * kt + 8);                  // B0(kt+2)
        stage(4 * kt + 9);                  // B1(kt+2)

        asm volatile("s_waitcnt lgkmcnt(4)" ::: "memory");   // A45 retired
        __builtin_amdgcn_sched_barrier(0);
        MFMA2(4, 5, a4, a5);
        asm volatile("s_waitcnt lgkmcnt(0)" ::: "memory");   // A67 retired
        __builtin_amdgcn_sched_barrier(0);
        MFMA2(6, 7, a6, a7);
        __builtin_amdgcn_s_barrier();       // #2: block-wide all A(kt) reads retired
        stage(4 * kt + 10);                 // A0(kt+2)

        if (kt < 14)       { asm volatile("s_waitcnt vmcnt(6)" ::: "memory"); }
        else if (kt == 14) { asm volatile("s_waitcnt vmcnt(0)" ::: "memory"); }
        __builtin_amdgcn_s_barrier();       // #3: tile kt+1 resident
    }

    // Epilogue. C/D layout: col = lr, row = lq*4 + reg (4 consecutive rows).
    if constexpr (MODE == 0) {
        const int wsel = n0 >> 10;                       // 0:Q 1:K 2:V (uniform per block)
        const int nb   = n0 & 1023;
        __hip_bfloat16* Op = Obf + (size_t)wsel * ((size_t)MM * KK);
        if (wsel == 0) {
            // Q: row-major bf16, elu+1
            #pragma unroll
            for (int i = 0; i < 8; ++i)
                #pragma unroll
                for (int j = 0; j < 4; ++j)
                    #pragma unroll
                    for (int r = 0; r < 4; ++r) {
                        const int row = m0 + warp_m * 128 + i * 16 + lq * 4 + r;
                        const int col = nb + warp_n * 64 + j * 16 + lr;
                        float v = acc[i][j][r];
                        v = (v > 0.f) ? v + 1.f : __expf(v);
                        Op[(size_t)row * 1024 + col] = __float2bfloat16(v);
                    }
        } else {
            // K (elu) / V: transposed [bh][hd][s] layout, packed 4-bf16 stores.
            // Lane's 4 regs are 4 consecutive s -> one aligned uint2 store.
            const bool doelu = (wsel == 1);
            #pragma unroll
            for (int i = 0; i < 8; ++i)
                #pragma unroll
                for (int j = 0; j < 4; ++j) {
                    const int row0 = m0 + warp_m * 128 + i * 16 + lq * 4;  // s base
                    const int col  = nb + warp_n * 64 + j * 16 + lr;       // h*64+hd
                    const int b    = row0 >> 12;
                    const int s    = row0 & 4095;
                    union { __hip_bfloat16 hh[4]; uint2 u; } pk;
                    #pragma unroll
                    for (int r = 0; r < 4; ++r) {
                        float v = acc[i][j][r];
                        if (doelu) v = (v > 0.f) ? v + 1.f : __expf(v);
                        pk.hh[r] = __float2bfloat16(v);
                    }
                    // bh = b*16 + (col>>6); d = col&63
                    *(uint2*)(Op + ((size_t)((b * 16 + (col >> 6)) * 64 + (col & 63)) * 4096 + s)) = pk.u;
                }
        }
    } else {
        #pragma unroll
        for (int i = 0; i < 8; ++i)
            #pragma unroll
            for (int j = 0; j < 4; ++j)
                #pragma unroll
                for (int r = 0; r < 4; ++r) {
                    const int row = m0 + warp_m * 128 + i * 16 + lq * 4 + r;
                    const int col = n0 + warp_n * 64 + j * 16 + lr;
                    Of32[(size_t)row * 1024 + col] = acc[i][j][r];
                }
    }
}

// ---------------------------------------------------------------------------
// KV + k_sum partials from TRANSPOSED K/V ([bh][d][s], s-contiguous).
// Per (bh, sp): C[64,64] = sum_s KT[d,s]*VT[e,s] over s-range 512.
// 4 waves x disjoint k=128; fragments are contiguous 16B global loads
// (4-lane lq-groups cover full 64B lines; data L2-resident per head).
// No LDS staging, no scalar gathers. Reduction/epilogue identical to the
// verified kv_mfma (same acc->sRed mapping: acc[i][j] = D[d-tile][e-tile]).
// ---------------------------------------------------------------------------
#define KV_SPLIT 8
__global__ __launch_bounds__(256)
void kv_gemm(const __hip_bfloat16* __restrict__ KB,
             const __hip_bfloat16* __restrict__ VB,
             float* __restrict__ KVp)
{
    __shared__ float sRed[65 * 66];

    const int bh = blockIdx.x;
    const int sp = blockIdx.y;
    const int t  = threadIdx.x;
    const int lane = t & 63;
    const int wv = t >> 6;
    const int lr = lane & 15;
    const int lq = lane >> 4;

    const __hip_bfloat16* kbase = KB + (size_t)bh * 64 * 4096;
    const __hip_bfloat16* vbase = VB + (size_t)bh * 64 * 4096;
    const int k0w = sp * 512 + wv * 128 + lq * 8;

    f32x4 acc[4][4];
    f32x4 ksacc[4];
    #pragma unroll
    for (int i = 0; i < 4; i++) {
        ksacc[i] = (f32x4){0.f, 0.f, 0.f, 0.f};
        #pragma unroll
        for (int j = 0; j < 4; j++)
            acc[i][j] = (f32x4){0.f, 0.f, 0.f, 0.f};
    }

    bf16x8 ones;
    #pragma unroll
    for (int j = 0; j < 8; j++) ones[j] = (__bf16)1.0f;

    #pragma unroll
    for (int c = 0; c < 4; ++c) {
        const int k0 = k0w + c * 32;
        bf16x8 ak[4], bv[4];
        #pragma unroll
        for (int i = 0; i < 4; ++i) {
            ak[i] = *(const bf16x8*)(kbase + (size_t)(i * 16 + lr) * 4096 + k0);
            bv[i] = *(const bf16x8*)(vbase + (size_t)(i * 16 + lr) * 4096 + k0);
        }
        #pragma unroll
        for (int i = 0; i < 4; ++i) {
            #pragma unroll
            for (int j = 0; j < 4; ++j)
                acc[i][j] = __builtin_amdgcn_mfma_f32_16x16x32_bf16(ak[i], bv[j], acc[i][j], 0, 0, 0);
            ksacc[i] = __builtin_amdgcn_mfma_f32_16x16x32_bf16(ak[i], ones, ksacc[i], 0, 0, 0);
        }
    }

    for (int w = 0; w < 4; w++) {
        if (wv == w) {
            #pragma unroll
            for (int i = 0; i < 4; i++) {
                #pragma unroll
                for (int j = 0; j < 4; j++) {
                    float* p = &sRed[(j * 16 + lr) * 66 + i * 16 + lq * 4];
                    if (w == 0) {
                        #pragma unroll
                        for (int r = 0; r < 4; r++) p[r] = acc[i][j][r];
                    } else {
                        #pragma unroll
                        for (int r = 0; r < 4; r++) p[r] += acc[i][j][r];
                    }
                }
                if (lr == 0) {
                    float* p = &sRed[64 * 66 + i * 16 + lq * 4];
                    if (w == 0) {
                        #pragma unroll
                        for (int r = 0; r < 4; r++) p[r] = ksacc[i][r];
                    } else {
                        #pragma unroll
                        for (int r = 0; r < 4; r++) p[r] += ksacc[i][r];
                    }
                }
            }
        }
        __syncthreads();
    }

    float* outp = KVp + (size_t)(sp * 64 + bh) * (65 * 64);
    #pragma unroll
    for (int i = 0; i < 17; i++) {
        int idx = i * 256 + t;
        if (idx < 65 * 64) {
            int e = idx >> 6, d = idx & 63;
            outp[idx] = sRed[e * 66 + d];
        }
    }
}

// ---------------------------------------------------------------------------
// Reduce partials -> KVt (bf16 [bh][e][d]) + KS (f32) (unchanged)
// ---------------------------------------------------------------------------
__global__ __launch_bounds__(256)
void kv_reduce(const float* __restrict__ KVp,
               __hip_bfloat16* __restrict__ KVt,
               float* __restrict__ KS)
{
    const int bh = blockIdx.x;
    const int t  = threadIdx.x;
    #pragma unroll
    for (int i = 0; i < 16; i++) {
        int idx = i * 256 + t;
        float s = 0.f;
        #pragma unroll
        for (int sp = 0; sp < KV_SPLIT; sp++)
            s += KVp[((size_t)(sp * 64 + bh) * 65) * 64 + idx];
        KVt[(size_t)bh * 4096 + idx] = __float2bfloat16(s);
    }
    if (t < 64) {
        float s = 0.f;
        #pragma unroll
        for (int sp = 0; sp < KV_SPLIT; sp++)
            s += KVp[((size_t)(sp * 64 + bh) * 65 + 64) * 64 + t];
        KS[bh * 64 + t] = s;
    }
}

// ---------------------------------------------------------------------------
// MFMA attention apply (unchanged — verified)
// ---------------------------------------------------------------------------
__global__ __launch_bounds__(256)
void attn_mfma(const __hip_bfloat16* __restrict__ Q,
               const __hip_bfloat16* __restrict__ KVt,
               const float* __restrict__ KS,
               __hip_bfloat16* __restrict__ O)
{
    const int bh = blockIdx.x;
    const int b  = bh >> 4;
    const int h  = bh & 15;
    const int s0 = blockIdx.y * 128;
    const int t  = threadIdx.x;
    const int lane = t & 63;
    const int wv = t >> 6;

    __shared__ __align__(16) __hip_bfloat16 sQ[128][72];
    __shared__ __align__(16) __hip_bfloat16 sKVt[64][72];
    __shared__ float sKS[64];
    __shared__ float sZ[128];

    {
        const float4* kvp = (const float4*)(KVt + (size_t)bh * 4096);
        #pragma unroll
        for (int i = 0; i < 2; i++) {
            int c = i * 256 + t;
            *(float4*)(&sKVt[c >> 3][(c & 7) * 8]) = kvp[c];
        }
        if (t < 64) sKS[t] = KS[bh * 64 + t];
    }
    {
        const __hip_bfloat16* qp = Q + ((size_t)b * SS + s0) * DD + h * HD;
        int r  = t >> 1;
        int c0 = (t & 1) * 32;
        #pragma unroll
        for (int i = 0; i < 32; i += 8)
            *(float4*)(&sQ[r][c0 + i]) = *(const float4*)(qp + (size_t)r * DD + c0 + i);
    }
    __syncthreads();

    if (t < 128) {
        float z = 0.f;
        #pragma unroll
        for (int d8 = 0; d8 < 64; d8 += 8) {
            bf16x8 qv = *(const bf16x8*)(&sQ[t][d8]);
            #pragma unroll
            for (int j = 0; j < 8; j++) z += (float)qv[j] * sKS[d8 + j];
        }
        sZ[t] = 1.f / (z + 1e-6f);
    }

    const int lr = lane & 15;
    const int lq = lane >> 4;
    f32x4 acc[2][4];
    #pragma unroll
    for (int i = 0; i < 2; i++)
        #pragma unroll
        for (int j = 0; j < 4; j++)
            acc[i][j] = (f32x4){0.f, 0.f, 0.f, 0.f};

    bf16x8 af[2][2], bfv[4][2];
    #pragma unroll
    for (int ks = 0; ks < 2; ks++) {
        #pragma unroll
        for (int i = 0; i < 2; i++)
            af[i][ks] = *(const bf16x8*)(&sQ[wv * 32 + i * 16 + lr][lq * 8 + ks * 32]);
        #pragma unroll
        for (int j = 0; j < 4; j++)
            bfv[j][ks] = *(const bf16x8*)(&sKVt[j * 16 + lr][lq * 8 + ks * 32]);
    }
    #pragma unroll
    for (int i = 0; i < 2; i++)
        #pragma unroll
        for (int j = 0; j < 4; j++) {
            acc[i][j] = __builtin_amdgcn_mfma_f32_16x16x32_bf16(af[i][0], bfv[j][0], acc[i][j], 0, 0, 0);
            acc[i][j] = __builtin_amdgcn_mfma_f32_16x16x32_bf16(af[i][1], bfv[j][1], acc[i][j], 0, 0, 0);
        }
    __syncthreads();

    __hip_bfloat16* op = O + ((size_t)b * SS + s0) * DD + h * HD;
    #pragma unroll
    for (int i = 0; i < 2; i++)
        #pragma unroll
        for (int j = 0; j < 4; j++)
            #pragma unroll
            for (int r = 0; r < 4; r++) {
                int row = wv * 32 + i * 16 + lq * 4 + r;
                int col = j * 16 + lr;
                op[(size_t)row * DD + col] = __float2bfloat16(acc[i][j][r] * sZ[row]);
            }
}

// ---------------------------------------------------------------------------
// launch
// ---------------------------------------------------------------------------
extern "C" void kernel_launch(void* const* d_in, const int* in_sizes, int n_in,
                              void* d_out, int out_size, void* d_ws, size_t ws_size,
                              hipStream_t stream) {
    const float* x  = (const float*)d_in[0];
    const float* Wq = (const float*)d_in[1];
    const float* Wk = (const float*)d_in[2];
    const float* Wv = (const float*)d_in[3];
    const float* Wo = (const float*)d_in[4];
    float* out = (float*)d_out;

    char* ws = (char*)d_ws;
    const size_t XB_BYTES = (size_t)MM * KK * 2;   // 32MB
    const size_t WB_BYTES = (size_t)NN * KK * 2;   // 2MB
    __hip_bfloat16* xb  = (__hip_bfloat16*)(ws);
    __hip_bfloat16* wqb = (__hip_bfloat16*)(ws + XB_BYTES);
    __hip_bfloat16* wkb = (__hip_bfloat16*)(ws + XB_BYTES + WB_BYTES);
    __hip_bfloat16* wvb = (__hip_bfloat16*)(ws + XB_BYTES + 2 * WB_BYTES);
    __hip_bfloat16* wob = (__hip_bfloat16*)(ws + XB_BYTES + 3 * WB_BYTES);
    __hip_bfloat16* qb  = (__hip_bfloat16*)(ws + XB_BYTES + 4 * WB_BYTES);
    __hip_bfloat16* kb  = (__hip_bfloat16*)(ws + 2 * XB_BYTES + 4 * WB_BYTES);  // K^T [bh][d][s]
    __hip_bfloat16* vb  = (__hip_bfloat16*)(ws + 3 * XB_BYTES + 4 * WB_BYTES);  // V^T [bh][d][s]
    __hip_bfloat16* KVt = (__hip_bfloat16*)(ws + 4 * XB_BYTES + 4 * WB_BYTES);          // 512KB
    float*          KS  = (float*)(ws + 4 * XB_BYTES + 4 * WB_BYTES + 524288);          // 16KB
    // KV partials (8.3MB f32) overlay xb (dead after QKV GEMM; attn writes
    // ab=xb only after kv_reduce). Stream-ordered, safe.
    float* KVp = (float*)(ws);
    __hip_bfloat16* ab = xb;

    const int XN = MM * KK;
    const int WN = NN * KK;

    // 1. convert inputs to bf16 (wqb|wkb|wvb contiguous -> one [3072][1024] B)
    cvt_f32_bf16<<<XN / 4 / 256, 256, 0, stream>>>(x,  xb,  XN / 4);
    cvt_f32_bf16<<<WN / 4 / 256, 256, 0, stream>>>(Wq, wqb, WN / 4);
    cvt_f32_bf16<<<WN / 4 / 256, 256, 0, stream>>>(Wk, wkb, WN / 4);
    cvt_f32_bf16<<<WN / 4 / 256, 256, 0, stream>>>(Wv, wvb, WN / 4);
    cvt_f32_bf16<<<WN / 4 / 256, 256, 0, stream>>>(Wo, wob, WN / 4);

    // 2. fused QKV projection: [16384,1024] @ [3072,1024]^T.
    //    Q -> qb row-major (+elu); K,V -> kb,vb TRANSPOSED [bh][d][s].
    gemm256<0><<<768, 512, 0, stream>>>(xb, wqb, qb, nullptr);

    // 3. KV + k_sum partials (clean B^T GEMM on transposed K/V), then reduce
    kv_gemm<<<dim3(BB * HH, KV_SPLIT), 256, 0, stream>>>(kb, vb, KVp);
    kv_reduce<<<BB * HH, 256, 0, stream>>>(KVp, KVt, KS);

    // 4. attention output (normalized), bf16, MFMA
    attn_mfma<<<dim3(BB * HH, SS / 128), 256, 0, stream>>>(qb, KVt, KS, ab);

    // 5. final projection -> fp32 d_out
    gemm256<1><<<256, 512, 0, stream>>>(ab, wob, nullptr, out);
}

// Round 7
// 324.810 us; speedup vs baseline: 1.1582x; 1.0346x over previous
//
#include <hip/hip_runtime.h>
#include <hip/hip_bf16.h>

// Problem constants (fixed by reference setup_inputs)
#define BB 4
#define SS 4096
#define DD 1024
#define HH 16
#define HD 64
#define MM (BB * SS)      // 16384
#define KK DD             // 1024
#define NN DD             // 1024

typedef __bf16 bf16x8 __attribute__((ext_vector_type(8)));
typedef float f32x4 __attribute__((ext_vector_type(4)));

typedef __attribute__((address_space(3))) void lds_void_t;
typedef const __attribute__((address_space(1))) void glb_void_t;

// ---------------------------------------------------------------------------
// Fused fp32 -> bf16 conversion for ALL inputs in one launch.
// Region select is blockIdx-range based -> wave-uniform branches, no
// runtime-indexed pointer arrays (rule #20 safe).
// Layout: xb (XN elems) | wq | wk | wv | wo (WN each), contiguous in ws.
// grid = XN/1024 + 4*WN/1024 = 16384 + 4096 = 20480 blocks.
// ---------------------------------------------------------------------------
__global__ __launch_bounds__(256)
void cvt_all(const float* __restrict__ x,
             const float* __restrict__ wq, const float* __restrict__ wk,
             const float* __restrict__ wv, const float* __restrict__ wo,
             __hip_bfloat16* __restrict__ base)
{
    const int blk = blockIdx.x;
    const float* src;
    __hip_bfloat16* dst;
    int i;
    if (blk < (MM * KK / 1024)) {              // x region: 16384 blocks
        src = x;
        dst = base;
        i = blk * 256 + threadIdx.x;
    } else {
        const int r = blk - (MM * KK / 1024);  // 0..4095
        const int w = r >> 10;                 // 0..3 (1024 blocks per weight)
        src = (w == 0) ? wq : (w == 1) ? wk : (w == 2) ? wv : wo;
        dst = base + (size_t)(MM * KK) + (size_t)w * (NN * KK);
        i = (r & 1023) * 256 + threadIdx.x;
    }
    float4 v = ((const float4*)src)[i];
    union { __hip_bfloat16 h[4]; uint2 u; } p;
    p.h[0] = __float2bfloat16(v.x);
    p.h[1] = __float2bfloat16(v.y);
    p.h[2] = __float2bfloat16(v.z);
    p.h[3] = __float2bfloat16(v.w);
    ((uint2*)dst)[i] = p.u;
}

// ---------------------------------------------------------------------------
// 256x256-tile, BK=64, 8-wave GEMM with counted-lgkmcnt clusters.
//   C[M,N] = A[M,K] @ B[N,K]^T, K = 1024 (16 K-tiles of 64).
// MODE 0: N=3072 (concat Wq|Wk|Wv). Q third: bf16 row-major + elu+1.
//         K third: elu+1, TRANSPOSED [bh][hd][s] packed uint2 stores.
//         V third: TRANSPOSED [bh][hd][s] packed uint2 stores. grid=768.
// MODE 1: N=1024; f32 out row-major. grid=256.
//
// Block swizzle: XCD-pinned A-band (HW XCD = bid%8):
//   mt = (bid&7)*8 + (bid>>3)&7, nt = bid>>6  -> each XCD owns a fixed
// 8-m-tile band of A (4 MB, L2-resident). Verified R4: FETCH 204->75 MB.
//
// R7 change: NO sched_barrier walls around read groups / MFMA clusters —
// the "memory"-clobber asm waits already pin all memory-op ordering (so the
// counted-wait FIFO ledger is exact), and the compiler is free to interleave
// ds_reads + address VALU into the MFMA clusters (m141 lesson: order-pinning
// defeats the scheduler). The ONLY kept sched_barriers are rule #18: right
// after each counted lgkmcnt wait, to stop register-only MFMA hoisting.
//
// Per K-tile (3 barriers, counted waits):
//   issue [B x8][A01 x4][A23 x4]; stage A1(kt+1)
//   lgkmcnt(4)+SB  -> B+A01 retired ; MFMA c0 ; issue [A45][A67]
//   lgkmcnt(8)+SB  -> A23 retired   ; MFMA c1
//   BARRIER #1 -> block-wide B(kt) reads retired ; stage B0,B1(kt+2)
//   lgkmcnt(4)+SB  -> A45 retired   ; MFMA c2
//   lgkmcnt(0)+SB  -> A67 retired   ; MFMA c3
//   BARRIER #2 -> all A(kt) reads retired ; stage A0(kt+2)
//   vmcnt(6) [vmcnt(0) at kt=14] ; BARRIER #3 -> tile kt+1 resident
// vmcnt ledger (FIFO, 2 loads/stage): per tile issues {A1(t+1),B0,B1,A0(t+2)};
// vmcnt(6) at tile end leaves exactly B0,B1,A0(t+2) in flight.
// LDS swizzle: logical (row,cb) at physical cb ^ ((row&7)<<4); inverse swizzle
// on the GLOBAL source (global_load_lds dest stays linear), same XOR on
// ds_read addresses (row&7 == lr&7 -> lane constant). 0 bank conflicts (R2+).
// ---------------------------------------------------------------------------
#define RD_A(dst, idx)                                                                   \
    dst[0] = *(const bf16x8*)(sAb + ((idx) * 16 + lr) * 128 + ((lq * 16) ^ swz));        \
    dst[1] = *(const bf16x8*)(sAb + ((idx) * 16 + lr) * 128 + (((64) + lq * 16) ^ swz));

#define MFMA2(i0, i1, va, vb)                                                                         \
    __builtin_amdgcn_s_setprio(1);                                                                    \
    _Pragma("unroll")                                                                                 \
    for (int j = 0; j < 4; ++j) {                                                                     \
        acc[i0][j] = __builtin_amdgcn_mfma_f32_16x16x32_bf16(va[0], bfr[j][0], acc[i0][j], 0, 0, 0);  \
        acc[i0][j] = __builtin_amdgcn_mfma_f32_16x16x32_bf16(va[1], bfr[j][1], acc[i0][j], 0, 0, 0);  \
        acc[i1][j] = __builtin_amdgcn_mfma_f32_16x16x32_bf16(vb[0], bfr[j][0], acc[i1][j], 0, 0, 0);  \
        acc[i1][j] = __builtin_amdgcn_mfma_f32_16x16x32_bf16(vb[1], bfr[j][1], acc[i1][j], 0, 0, 0);  \
    }                                                                                                 \
    __builtin_amdgcn_s_setprio(0);

template<int MODE>
__global__ __launch_bounds__(512, 2)
void gemm256(const __hip_bfloat16* __restrict__ Ain,
             const __hip_bfloat16* __restrict__ Bin,
             __hip_bfloat16* __restrict__ Obf,
             float* __restrict__ Of32)
{
    __shared__ __align__(16) __hip_bfloat16 sA[2][2][128 * 64];
    __shared__ __align__(16) __hip_bfloat16 sB[2][2][128 * 64];

    // XCD-pinned A-band swizzle.
    const int bid = blockIdx.x;
    const int mt  = ((bid & 7) << 3) | ((bid >> 3) & 7);
    const int nt  = bid >> 6;
    const int m0  = mt << 8;
    const int n0  = nt << 8;

    const int t      = threadIdx.x;
    const int lane   = t & 63;
    const int w      = t >> 6;
    const int warp_m = w >> 2;             // 0..1  -> A half
    const int warp_n = w & 3;              // 0..3
    const int halfB  = warp_n >> 1;        // B half
    const int bn     = (warp_n & 1) << 6;  // 0/64 within B half
    const int lr     = lane & 15;
    const int lq     = lane >> 4;
    const int swz    = (lr & 7) << 4;      // read-side XOR (row&7 == lr&7)

    const int trow = t >> 3;
    const int tcb  = (((t & 7) ^ ((t >> 3) & 7)) << 4);  // inverse-swizzled src col-byte

    auto stage = [&](int ht) {             // ht = tile*4 + {0:B0,1:B1,2:A0,3:A1}
        if (ht >= 64) return;
        const int ts   = ht >> 2;
        const int kind = ht & 3;
        const int half = kind & 1;
        #pragma unroll
        for (int i = 0; i < 2; ++i) {
            const int row = i * 64 + trow;
            if (kind >= 2) {
                __builtin_amdgcn_global_load_lds(
                    (glb_void_t*)(Ain + (size_t)(m0 + half * 128 + row) * 1024 + ts * 64 + (tcb >> 1)),
                    (lds_void_t*)(&sA[ts & 1][half][(i * 512 + t) * 8]), 16, 0, 0);
            } else {
                __builtin_amdgcn_global_load_lds(
                    (glb_void_t*)(Bin + (size_t)(n0 + half * 128 + row) * 1024 + ts * 64 + (tcb >> 1)),
                    (lds_void_t*)(&sB[ts & 1][half][(i * 512 + t) * 8]), 16, 0, 0);
            }
        }
    };

    f32x4 acc[8][4];
    #pragma unroll
    for (int i = 0; i < 8; ++i)
        #pragma unroll
        for (int j = 0; j < 4; ++j)
            acc[i][j] = (f32x4){0.f, 0.f, 0.f, 0.f};

    // Prologue: tile0 (4 half-tiles) + tile1's B0,B1,A0 in flight.
    stage(0); stage(1); stage(2); stage(3);
    stage(4); stage(5); stage(6);
    asm volatile("s_waitcnt vmcnt(6)" ::: "memory");
    __builtin_amdgcn_s_barrier();

    #pragma unroll 2
    for (int kt = 0; kt < 16; ++kt) {
        const char* sAb = (const char*)&sA[kt & 1][warp_m][0];
        const char* sBb = (const char*)&sB[kt & 1][halfB][0];
        bf16x8 bfr[4][2];
        bf16x8 a0[2], a1[2], a2[2], a3[2], a4[2], a5[2], a6[2], a7[2];

        // issue [B x8] [A01 x4] [A23 x4] (order pinned only by asm waits)
        #pragma unroll
        for (int j = 0; j < 4; ++j) {
            bfr[j][0] = *(const bf16x8*)(sBb + (bn + j * 16 + lr) * 128 + ((lq * 16) ^ swz));
            bfr[j][1] = *(const bf16x8*)(sBb + (bn + j * 16 + lr) * 128 + ((64 + lq * 16) ^ swz));
        }
        RD_A(a0, 0); RD_A(a1, 1);
        RD_A(a2, 2); RD_A(a3, 3);
        stage(4 * kt + 7);                  // A1(kt+1) -> other buffer

        asm volatile("s_waitcnt lgkmcnt(4)" ::: "memory");   // B + A01 retired
        __builtin_amdgcn_sched_barrier(0);                   // rule #18
        MFMA2(0, 1, a0, a1);
        RD_A(a4, 4); RD_A(a5, 5);          // [A45] (free to interleave into c0/c1)
        RD_A(a6, 6); RD_A(a7, 7);          // [A67]

        asm volatile("s_waitcnt lgkmcnt(8)" ::: "memory");   // A23 retired
        __builtin_amdgcn_sched_barrier(0);                   // rule #18
        MFMA2(2, 3, a2, a3);
        __builtin_amdgcn_s_barrier();       // #1: block-wide B(kt) reads retired
        stage(4 * kt + 8);                  // B0(kt+2)
        stage(4 * kt + 9);                  // B1(kt+2)

        asm volatile("s_waitcnt lgkmcnt(4)" ::: "memory");   // A45 retired
        __builtin_amdgcn_sched_barrier(0);                   // rule #18
        MFMA2(4, 5, a4, a5);
        asm volatile("s_waitcnt lgkmcnt(0)" ::: "memory");   // A67 retired
        __builtin_amdgcn_sched_barrier(0);                   // rule #18
        MFMA2(6, 7, a6, a7);
        __builtin_amdgcn_s_barrier();       // #2: block-wide all A(kt) reads retired
        stage(4 * kt + 10);                 // A0(kt+2)

        if (kt < 14)       { asm volatile("s_waitcnt vmcnt(6)" ::: "memory"); }
        else if (kt == 14) { asm volatile("s_waitcnt vmcnt(0)" ::: "memory"); }
        __builtin_amdgcn_s_barrier();       // #3: tile kt+1 resident
    }

    // Epilogue. C/D layout: col = lr, row = lq*4 + reg (4 consecutive rows).
    if constexpr (MODE == 0) {
        const int wsel = n0 >> 10;                       // 0:Q 1:K 2:V (uniform per block)
        const int nb   = n0 & 1023;
        __hip_bfloat16* Op = Obf + (size_t)wsel * ((size_t)MM * KK);
        if (wsel == 0) {
            // Q: row-major bf16, elu+1
            #pragma unroll
            for (int i = 0; i < 8; ++i)
                #pragma unroll
                for (int j = 0; j < 4; ++j)
                    #pragma unroll
                    for (int r = 0; r < 4; ++r) {
                        const int row = m0 + warp_m * 128 + i * 16 + lq * 4 + r;
                        const int col = nb + warp_n * 64 + j * 16 + lr;
                        float v = acc[i][j][r];
                        v = (v > 0.f) ? v + 1.f : __expf(v);
                        Op[(size_t)row * 1024 + col] = __float2bfloat16(v);
                    }
        } else {
            // K (elu) / V: transposed [bh][hd][s] layout, packed 4-bf16 stores.
            const bool doelu = (wsel == 1);
            #pragma unroll
            for (int i = 0; i < 8; ++i)
                #pragma unroll
                for (int j = 0; j < 4; ++j) {
                    const int row0 = m0 + warp_m * 128 + i * 16 + lq * 4;  // s base
                    const int col  = nb + warp_n * 64 + j * 16 + lr;       // h*64+hd
                    const int b    = row0 >> 12;
                    const int s    = row0 & 4095;
                    union { __hip_bfloat16 hh[4]; uint2 u; } pk;
                    #pragma unroll
                    for (int r = 0; r < 4; ++r) {
                        float v = acc[i][j][r];
                        if (doelu) v = (v > 0.f) ? v + 1.f : __expf(v);
                        pk.hh[r] = __float2bfloat16(v);
                    }
                    *(uint2*)(Op + ((size_t)((b * 16 + (col >> 6)) * 64 + (col & 63)) * 4096 + s)) = pk.u;
                }
        }
    } else {
        #pragma unroll
        for (int i = 0; i < 8; ++i)
            #pragma unroll
            for (int j = 0; j < 4; ++j)
                #pragma unroll
                for (int r = 0; r < 4; ++r) {
                    const int row = m0 + warp_m * 128 + i * 16 + lq * 4 + r;
                    const int col = n0 + warp_n * 64 + j * 16 + lr;
                    Of32[(size_t)row * 1024 + col] = acc[i][j][r];
                }
    }
}

// ---------------------------------------------------------------------------
// KV + k_sum partials from TRANSPOSED K/V ([bh][d][s], s-contiguous).
// (unchanged — verified R6)
// ---------------------------------------------------------------------------
#define KV_SPLIT 8
__global__ __launch_bounds__(256)
void kv_gemm(const __hip_bfloat16* __restrict__ KB,
             const __hip_bfloat16* __restrict__ VB,
             float* __restrict__ KVp)
{
    __shared__ float sRed[65 * 66];

    const int bh = blockIdx.x;
    const int sp = blockIdx.y;
    const int t  = threadIdx.x;
    const int lane = t & 63;
    const int wv = t >> 6;
    const int lr = lane & 15;
    const int lq = lane >> 4;

    const __hip_bfloat16* kbase = KB + (size_t)bh * 64 * 4096;
    const __hip_bfloat16* vbase = VB + (size_t)bh * 64 * 4096;
    const int k0w = sp * 512 + wv * 128 + lq * 8;

    f32x4 acc[4][4];
    f32x4 ksacc[4];
    #pragma unroll
    for (int i = 0; i < 4; i++) {
        ksacc[i] = (f32x4){0.f, 0.f, 0.f, 0.f};
        #pragma unroll
        for (int j = 0; j < 4; j++)
            acc[i][j] = (f32x4){0.f, 0.f, 0.f, 0.f};
    }

    bf16x8 ones;
    #pragma unroll
    for (int j = 0; j < 8; j++) ones[j] = (__bf16)1.0f;

    #pragma unroll
    for (int c = 0; c < 4; ++c) {
        const int k0 = k0w + c * 32;
        bf16x8 ak[4], bv[4];
        #pragma unroll
        for (int i = 0; i < 4; ++i) {
            ak[i] = *(const bf16x8*)(kbase + (size_t)(i * 16 + lr) * 4096 + k0);
            bv[i] = *(const bf16x8*)(vbase + (size_t)(i * 16 + lr) * 4096 + k0);
        }
        #pragma unroll
        for (int i = 0; i < 4; ++i) {
            #pragma unroll
            for (int j = 0; j < 4; ++j)
                acc[i][j] = __builtin_amdgcn_mfma_f32_16x16x32_bf16(ak[i], bv[j], acc[i][j], 0, 0, 0);
            ksacc[i] = __builtin_amdgcn_mfma_f32_16x16x32_bf16(ak[i], ones, ksacc[i], 0, 0, 0);
        }
    }

    for (int w = 0; w < 4; w++) {
        if (wv == w) {
            #pragma unroll
            for (int i = 0; i < 4; i++) {
                #pragma unroll
                for (int j = 0; j < 4; j++) {
                    float* p = &sRed[(j * 16 + lr) * 66 + i * 16 + lq * 4];
                    if (w == 0) {
                        #pragma unroll
                        for (int r = 0; r < 4; r++) p[r] = acc[i][j][r];
                    } else {
                        #pragma unroll
                        for (int r = 0; r < 4; r++) p[r] += acc[i][j][r];
                    }
                }
                if (lr == 0) {
                    float* p = &sRed[64 * 66 + i * 16 + lq * 4];
                    if (w == 0) {
                        #pragma unroll
                        for (int r = 0; r < 4; r++) p[r] = ksacc[i][r];
                    } else {
                        #pragma unroll
                        for (int r = 0; r < 4; r++) p[r] += ksacc[i][r];
                    }
                }
            }
        }
        __syncthreads();
    }

    float* outp = KVp + (size_t)(sp * 64 + bh) * (65 * 64);
    #pragma unroll
    for (int i = 0; i < 17; i++) {
        int idx = i * 256 + t;
        if (idx < 65 * 64) {
            int e = idx >> 6, d = idx & 63;
            outp[idx] = sRed[e * 66 + d];
        }
    }
}

// ---------------------------------------------------------------------------
// Reduce partials -> KVt (bf16 [bh][e][d]) + KS (f32) (unchanged)
// ---------------------------------------------------------------------------
__global__ __launch_bounds__(256)
void kv_reduce(const float* __restrict__ KVp,
               __hip_bfloat16* __restrict__ KVt,
               float* __restrict__ KS)
{
    const int bh = blockIdx.x;
    const int t  = threadIdx.x;
    #pragma unroll
    for (int i = 0; i < 16; i++) {
        int idx = i * 256 + t;
        float s = 0.f;
        #pragma unroll
        for (int sp = 0; sp < KV_SPLIT; sp++)
            s += KVp[((size_t)(sp * 64 + bh) * 65) * 64 + idx];
        KVt[(size_t)bh * 4096 + idx] = __float2bfloat16(s);
    }
    if (t < 64) {
        float s = 0.f;
        #pragma unroll
        for (int sp = 0; sp < KV_SPLIT; sp++)
            s += KVp[((size_t)(sp * 64 + bh) * 65 + 64) * 64 + t];
        KS[bh * 64 + t] = s;
    }
}

// ---------------------------------------------------------------------------
// MFMA attention apply (unchanged — verified)
// ---------------------------------------------------------------------------
__global__ __launch_bounds__(256)
void attn_mfma(const __hip_bfloat16* __restrict__ Q,
               const __hip_bfloat16* __restrict__ KVt,
               const float* __restrict__ KS,
               __hip_bfloat16* __restrict__ O)
{
    const int bh = blockIdx.x;
    const int b  = bh >> 4;
    const int h  = bh & 15;
    const int s0 = blockIdx.y * 128;
    const int t  = threadIdx.x;
    const int lane = t & 63;
    const int wv = t >> 6;

    __shared__ __align__(16) __hip_bfloat16 sQ[128][72];
    __shared__ __align__(16) __hip_bfloat16 sKVt[64][72];
    __shared__ float sKS[64];
    __shared__ float sZ[128];

    {
        const float4* kvp = (const float4*)(KVt + (size_t)bh * 4096);
        #pragma unroll
        for (int i = 0; i < 2; i++) {
            int c = i * 256 + t;
            *(float4*)(&sKVt[c >> 3][(c & 7) * 8]) = kvp[c];
        }
        if (t < 64) sKS[t] = KS[bh * 64 + t];
    }
    {
        const __hip_bfloat16* qp = Q + ((size_t)b * SS + s0) * DD + h * HD;
        int r  = t >> 1;
        int c0 = (t & 1) * 32;
        #pragma unroll
        for (int i = 0; i < 32; i += 8)
            *(float4*)(&sQ[r][c0 + i]) = *(const float4*)(qp + (size_t)r * DD + c0 + i);
    }
    __syncthreads();

    if (t < 128) {
        float z = 0.f;
        #pragma unroll
        for (int d8 = 0; d8 < 64; d8 += 8) {
            bf16x8 qv = *(const bf16x8*)(&sQ[t][d8]);
            #pragma unroll
            for (int j = 0; j < 8; j++) z += (float)qv[j] * sKS[d8 + j];
        }
        sZ[t] = 1.f / (z + 1e-6f);
    }

    const int lr = lane & 15;
    const int lq = lane >> 4;
    f32x4 acc[2][4];
    #pragma unroll
    for (int i = 0; i < 2; i++)
        #pragma unroll
        for (int j = 0; j < 4; j++)
            acc[i][j] = (f32x4){0.f, 0.f, 0.f, 0.f};

    bf16x8 af[2][2], bfv[4][2];
    #pragma unroll
    for (int ks = 0; ks < 2; ks++) {
        #pragma unroll
        for (int i = 0; i < 2; i++)
            af[i][ks] = *(const bf16x8*)(&sQ[wv * 32 + i * 16 + lr][lq * 8 + ks * 32]);
        #pragma unroll
        for (int j = 0; j < 4; j++)
            bfv[j][ks] = *(const bf16x8*)(&sKVt[j * 16 + lr][lq * 8 + ks * 32]);
    }
    #pragma unroll
    for (int i = 0; i < 2; i++)
        #pragma unroll
        for (int j = 0; j < 4; j++) {
            acc[i][j] = __builtin_amdgcn_mfma_f32_16x16x32_bf16(af[i][0], bfv[j][0], acc[i][j], 0, 0, 0);
            acc[i][j] = __builtin_amdgcn_mfma_f32_16x16x32_bf16(af[i][1], bfv[j][1], acc[i][j], 0, 0, 0);
        }
    __syncthreads();

    __hip_bfloat16* op = O + ((size_t)b * SS + s0) * DD + h * HD;
    #pragma unroll
    for (int i = 0; i < 2; i++)
        #pragma unroll
        for (int j = 0; j < 4; j++)
            #pragma unroll
            for (int r = 0; r < 4; r++) {
                int row = wv * 32 + i * 16 + lq * 4 + r;
                int col = j * 16 + lr;
                op[(size_t)row * DD + col] = __float2bfloat16(acc[i][j][r] * sZ[row]);
            }
}

// ---------------------------------------------------------------------------
// launch
// ---------------------------------------------------------------------------
extern "C" void kernel_launch(void* const* d_in, const int* in_sizes, int n_in,
                              void* d_out, int out_size, void* d_ws, size_t ws_size,
                              hipStream_t stream) {
    const float* x  = (const float*)d_in[0];
    const float* Wq = (const float*)d_in[1];
    const float* Wk = (const float*)d_in[2];
    const float* Wv = (const float*)d_in[3];
    const float* Wo = (const float*)d_in[4];
    float* out = (float*)d_out;

    char* ws = (char*)d_ws;
    const size_t XB_BYTES = (size_t)MM * KK * 2;   // 32MB
    const size_t WB_BYTES = (size_t)NN * KK * 2;   // 2MB
    __hip_bfloat16* xb  = (__hip_bfloat16*)(ws);
    __hip_bfloat16* wqb = (__hip_bfloat16*)(ws + XB_BYTES);
    __hip_bfloat16* wob = (__hip_bfloat16*)(ws + XB_BYTES + 3 * WB_BYTES);
    __hip_bfloat16* qb  = (__hip_bfloat16*)(ws + XB_BYTES + 4 * WB_BYTES);
    __hip_bfloat16* kb  = (__hip_bfloat16*)(ws + 2 * XB_BYTES + 4 * WB_BYTES);  // K^T [bh][d][s]
    __hip_bfloat16* vb  = (__hip_bfloat16*)(ws + 3 * XB_BYTES + 4 * WB_BYTES);  // V^T [bh][d][s]
    __hip_bfloat16* KVt = (__hip_bfloat16*)(ws + 4 * XB_BYTES + 4 * WB_BYTES);          // 512KB
    float*          KS  = (float*)(ws + 4 * XB_BYTES + 4 * WB_BYTES + 524288);          // 16KB
    // KV partials (8.3MB f32) overlay xb (dead after QKV GEMM; attn writes
    // ab=xb only after kv_reduce). Stream-ordered, safe.
    float* KVp = (float*)(ws);
    __hip_bfloat16* ab = xb;

    // 1. convert ALL inputs to bf16 in one launch (xb | wq|wk|wv|wo contiguous)
    cvt_all<<<(MM * KK + 4 * NN * KK) / 1024, 256, 0, stream>>>(x, Wq, Wk, Wv, Wo, xb);

    // 2. fused QKV projection: [16384,1024] @ [3072,1024]^T.
    //    Q -> qb row-major (+elu); K,V -> kb,vb TRANSPOSED [bh][d][s].
    gemm256<0><<<768, 512, 0, stream>>>(xb, wqb, qb, nullptr);

    // 3. KV + k_sum partials (clean B^T GEMM on transposed K/V), then reduce
    kv_gemm<<<dim3(BB * HH, KV_SPLIT), 256, 0, stream>>>(kb, vb, KVp);
    kv_reduce<<<BB * HH, 256, 0, stream>>>(KVp, KVt, KS);

    // 4. attention output (normalized), bf16, MFMA
    attn_mfma<<<dim3(BB * HH, SS / 128), 256, 0, stream>>>(qb, KVt, KS, ab);

    // 5. final projection -> fp32 d_out
    gemm256<1><<<256, 512, 0, stream>>>(ab, wob, nullptr, out);
}

// Round 8
// 301.679 us; speedup vs baseline: 1.2471x; 1.0767x over previous
//
#include <hip/hip_runtime.h>
#include <hip/hip_bf16.h>

// Problem constants (fixed by reference setup_inputs)
#define BB 4
#define SS 4096
#define DD 1024
#define HH 16
#define HD 64
#define MM (BB * SS)      // 16384
#define KK DD             // 1024
#define NN DD             // 1024

typedef __bf16 bf16x8 __attribute__((ext_vector_type(8)));
typedef float f32x4 __attribute__((ext_vector_type(4)));

typedef __attribute__((address_space(3))) void lds_void_t;
typedef const __attribute__((address_space(1))) void glb_void_t;

// ---------------------------------------------------------------------------
// Fused fp32 -> bf16 conversion for ALL inputs in one launch (verified R7).
// ---------------------------------------------------------------------------
__global__ __launch_bounds__(256)
void cvt_all(const float* __restrict__ x,
             const float* __restrict__ wq, const float* __restrict__ wk,
             const float* __restrict__ wv, const float* __restrict__ wo,
             __hip_bfloat16* __restrict__ base)
{
    const int blk = blockIdx.x;
    const float* src;
    __hip_bfloat16* dst;
    int i;
    if (blk < (MM * KK / 1024)) {              // x region: 16384 blocks
        src = x;
        dst = base;
        i = blk * 256 + threadIdx.x;
    } else {
        const int r = blk - (MM * KK / 1024);  // 0..4095
        const int w = r >> 10;                 // 0..3 (1024 blocks per weight)
        src = (w == 0) ? wq : (w == 1) ? wk : (w == 2) ? wv : wo;
        dst = base + (size_t)(MM * KK) + (size_t)w * (NN * KK);
        i = (r & 1023) * 256 + threadIdx.x;
    }
    float4 v = ((const float4*)src)[i];
    union { __hip_bfloat16 h[4]; uint2 u; } p;
    p.h[0] = __float2bfloat16(v.x);
    p.h[1] = __float2bfloat16(v.y);
    p.h[2] = __float2bfloat16(v.z);
    p.h[3] = __float2bfloat16(v.w);
    ((uint2*)dst)[i] = p.u;
}

// ---------------------------------------------------------------------------
// 256x256-tile, BK=64, 8-wave GEMM — m201-exact 8-phase form (R8).
//   C[M,N] = A[M,K] @ B[N,K]^T, K = 1024 (16 K-tiles of 64).
// MODE 0: N=3072 (Wq|Wk|Wv). Q: row-major bf16 + elu+1; K: elu+1 transposed
//         [bh][hd][s] uint2; V: transposed uint2. grid=768.
// MODE 1: N=1024; f32 out row-major. grid=256.
//
// Block swizzle: XCD-pinned A-band (verified R4: FETCH 204->75 MB).
//
// R8 phasing (4 phases/K-tile, 2 barriers each, m201 template):
//   ph0: read 8 B-frags + A-frags 0,1 (12 ds) ; stage A0(kt+1) ; lgkm(8)
//        ; BAR ; lgkm(0)+SB ; MFMA(0,1) ; BAR
//   ph1: read A2,A3 ; stage A1(kt+1) ; BAR ; lgkm(0)+SB ; MFMA(2,3) ; BAR
//   ph2: read A4,A5 ; stage B0(kt+2) ; BAR ; lgkm(0)+SB ; MFMA(4,5) ; BAR
//   ph3: read A6,A7 ; stage B1(kt+2) ; BAR ; lgkm(0)+SB ; MFMA(6,7)
//        ; vmcnt(4) [vmcnt(0) @kt=14] ; BAR
// Reads issue BEFORE the leading barrier, wait AFTER it -> LDS drain hides
// under barrier skew + other wave's MFMA; per-phase wait depth is only 4.
// STRICT stage safety (no latency assumptions):
//   A0/A1(kt+1) -> opposite-parity buffer; its last readers (tile kt-1)
//     finished before kt-1's final barrier, which precedes these stages.
//   B0/B1(kt+2) -> same-parity B; all B(kt) frag reads retire before ph0's
//     trailing barrier, which precedes ph2/ph3.
// vmcnt FIFO ledger (2 loads/stage): tile kt issues {A0,A1(kt+1),B0,B1(kt+2)}
//   = 8 loads; at tile end outstanding=12, retiring oldest 8 completes tile
//   kt+1 -> vmcnt(4). Prologue: t0 (8 loads) + B0,B1(t1) (4) -> vmcnt(4).
// LDS swizzle: (row,cb) at cb ^ ((row&7)<<4); inverse on global source,
// same XOR on ds_read (row&7 == lr&7 -> lane const). 0 conflicts (R2+).
// ---------------------------------------------------------------------------
#define RD_A(dst, idx)                                                                   \
    dst[0] = *(const bf16x8*)(sAb + ((idx) * 16 + lr) * 128 + ((lq * 16) ^ swz));        \
    dst[1] = *(const bf16x8*)(sAb + ((idx) * 16 + lr) * 128 + (((64) + lq * 16) ^ swz));

#define MFMA2(i0, i1, va, vb)                                                                         \
    __builtin_amdgcn_s_setprio(1);                                                                    \
    _Pragma("unroll")                                                                                 \
    for (int j = 0; j < 4; ++j) {                                                                     \
        acc[i0][j] = __builtin_amdgcn_mfma_f32_16x16x32_bf16(va[0], bfr[j][0], acc[i0][j], 0, 0, 0);  \
        acc[i0][j] = __builtin_amdgcn_mfma_f32_16x16x32_bf16(va[1], bfr[j][1], acc[i0][j], 0, 0, 0);  \
        acc[i1][j] = __builtin_amdgcn_mfma_f32_16x16x32_bf16(vb[0], bfr[j][0], acc[i1][j], 0, 0, 0);  \
        acc[i1][j] = __builtin_amdgcn_mfma_f32_16x16x32_bf16(vb[1], bfr[j][1], acc[i1][j], 0, 0, 0);  \
    }                                                                                                 \
    __builtin_amdgcn_s_setprio(0);

#define PH_ENTER                                                \
    __builtin_amdgcn_s_barrier();                               \
    asm volatile("s_waitcnt lgkmcnt(0)" ::: "memory");          \
    __builtin_amdgcn_sched_barrier(0);

template<int MODE>
__global__ __launch_bounds__(512, 2)
void gemm256(const __hip_bfloat16* __restrict__ Ain,
             const __hip_bfloat16* __restrict__ Bin,
             __hip_bfloat16* __restrict__ Obf,
             float* __restrict__ Of32)
{
    __shared__ __align__(16) __hip_bfloat16 sA[2][2][128 * 64];
    __shared__ __align__(16) __hip_bfloat16 sB[2][2][128 * 64];

    // XCD-pinned A-band swizzle.
    const int bid = blockIdx.x;
    const int mt  = ((bid & 7) << 3) | ((bid >> 3) & 7);
    const int nt  = bid >> 6;
    const int m0  = mt << 8;
    const int n0  = nt << 8;

    const int t      = threadIdx.x;
    const int lane   = t & 63;
    const int w      = t >> 6;
    const int warp_m = w >> 2;             // 0..1  -> A half
    const int warp_n = w & 3;              // 0..3
    const int halfB  = warp_n >> 1;        // B half
    const int bn     = (warp_n & 1) << 6;  // 0/64 within B half
    const int lr     = lane & 15;
    const int lq     = lane >> 4;
    const int swz    = (lr & 7) << 4;      // read-side XOR (row&7 == lr&7)

    const int trow = t >> 3;
    const int tcb  = (((t & 7) ^ ((t >> 3) & 7)) << 4);  // inverse-swizzled src col-byte

    auto stage = [&](int ht) {             // ht = tile*4 + {0:B0,1:B1,2:A0,3:A1}
        if (ht >= 64) return;
        const int ts   = ht >> 2;
        const int kind = ht & 3;
        const int half = kind & 1;
        #pragma unroll
        for (int i = 0; i < 2; ++i) {
            const int row = i * 64 + trow;
            if (kind >= 2) {
                __builtin_amdgcn_global_load_lds(
                    (glb_void_t*)(Ain + (size_t)(m0 + half * 128 + row) * 1024 + ts * 64 + (tcb >> 1)),
                    (lds_void_t*)(&sA[ts & 1][half][(i * 512 + t) * 8]), 16, 0, 0);
            } else {
                __builtin_amdgcn_global_load_lds(
                    (glb_void_t*)(Bin + (size_t)(n0 + half * 128 + row) * 1024 + ts * 64 + (tcb >> 1)),
                    (lds_void_t*)(&sB[ts & 1][half][(i * 512 + t) * 8]), 16, 0, 0);
            }
        }
    };

    f32x4 acc[8][4];
    #pragma unroll
    for (int i = 0; i < 8; ++i)
        #pragma unroll
        for (int j = 0; j < 4; ++j)
            acc[i][j] = (f32x4){0.f, 0.f, 0.f, 0.f};

    // Prologue: t0 fully (B0,B1,A0,A1 = 8 loads) + B0,B1(t1) (4 loads).
    stage(0); stage(1); stage(2); stage(3);
    stage(4); stage(5);
    asm volatile("s_waitcnt vmcnt(4)" ::: "memory");   // t0 resident
    __builtin_amdgcn_s_barrier();

    #pragma unroll 2
    for (int kt = 0; kt < 16; ++kt) {
        const char* sAb = (const char*)&sA[kt & 1][warp_m][0];
        const char* sBb = (const char*)&sB[kt & 1][halfB][0];
        bf16x8 bfr[4][2];
        bf16x8 x0[2], x1[2];

        // ---- ph0: 8 B-frags + A0,A1 (12 ds) ; stage A0(kt+1)
        #pragma unroll
        for (int j = 0; j < 4; ++j) {
            bfr[j][0] = *(const bf16x8*)(sBb + (bn + j * 16 + lr) * 128 + ((lq * 16) ^ swz));
            bfr[j][1] = *(const bf16x8*)(sBb + (bn + j * 16 + lr) * 128 + ((64 + lq * 16) ^ swz));
        }
        RD_A(x0, 0); RD_A(x1, 1);
        stage(4 * (kt + 1) + 2);            // A0(kt+1) -> opposite parity, safe
        asm volatile("s_waitcnt lgkmcnt(8)" ::: "memory");   // drain B burst head
        PH_ENTER;
        MFMA2(0, 1, x0, x1);
        __builtin_amdgcn_s_barrier();       // B(kt) reads block-retired here

        // ---- ph1: A2,A3 ; stage A1(kt+1)
        RD_A(x0, 2); RD_A(x1, 3);
        stage(4 * (kt + 1) + 3);            // A1(kt+1) -> opposite parity, safe
        PH_ENTER;
        MFMA2(2, 3, x0, x1);
        __builtin_amdgcn_s_barrier();

        // ---- ph2: A4,A5 ; stage B0(kt+2)
        RD_A(x0, 4); RD_A(x1, 5);
        stage(4 * (kt + 2) + 0);            // B0(kt+2): B(kt) reads done @ph0-trail
        PH_ENTER;
        MFMA2(4, 5, x0, x1);
        __builtin_amdgcn_s_barrier();

        // ---- ph3: A6,A7 ; stage B1(kt+2)
        RD_A(x0, 6); RD_A(x1, 7);
        stage(4 * (kt + 2) + 1);            // B1(kt+2)
        PH_ENTER;
        MFMA2(6, 7, x0, x1);
        if (kt < 14)       { asm volatile("s_waitcnt vmcnt(4)" ::: "memory"); }
        else if (kt == 14) { asm volatile("s_waitcnt vmcnt(0)" ::: "memory"); }
        __builtin_amdgcn_s_barrier();       // tile kt+1 resident
    }

    // Epilogue. C/D layout: col = lr, row = lq*4 + reg (4 consecutive rows).
    if constexpr (MODE == 0) {
        const int wsel = n0 >> 10;                       // 0:Q 1:K 2:V (uniform per block)
        const int nb   = n0 & 1023;
        __hip_bfloat16* Op = Obf + (size_t)wsel * ((size_t)MM * KK);
        if (wsel == 0) {
            #pragma unroll
            for (int i = 0; i < 8; ++i)
                #pragma unroll
                for (int j = 0; j < 4; ++j)
                    #pragma unroll
                    for (int r = 0; r < 4; ++r) {
                        const int row = m0 + warp_m * 128 + i * 16 + lq * 4 + r;
                        const int col = nb + warp_n * 64 + j * 16 + lr;
                        float v = acc[i][j][r];
                        v = (v > 0.f) ? v + 1.f : __expf(v);
                        Op[(size_t)row * 1024 + col] = __float2bfloat16(v);
                    }
        } else {
            // K (elu) / V: transposed [bh][hd][s], packed 4-bf16 stores.
            const bool doelu = (wsel == 1);
            #pragma unroll
            for (int i = 0; i < 8; ++i)
                #pragma unroll
                for (int j = 0; j < 4; ++j) {
                    const int row0 = m0 + warp_m * 128 + i * 16 + lq * 4;  // s base
                    const int col  = nb + warp_n * 64 + j * 16 + lr;       // h*64+hd
                    const int b    = row0 >> 12;
                    const int s    = row0 & 4095;
                    union { __hip_bfloat16 hh[4]; uint2 u; } pk;
                    #pragma unroll
                    for (int r = 0; r < 4; ++r) {
                        float v = acc[i][j][r];
                        if (doelu) v = (v > 0.f) ? v + 1.f : __expf(v);
                        pk.hh[r] = __float2bfloat16(v);
                    }
                    *(uint2*)(Op + ((size_t)((b * 16 + (col >> 6)) * 64 + (col & 63)) * 4096 + s)) = pk.u;
                }
        }
    } else {
        #pragma unroll
        for (int i = 0; i < 8; ++i)
            #pragma unroll
            for (int j = 0; j < 4; ++j)
                #pragma unroll
                for (int r = 0; r < 4; ++r) {
                    const int row = m0 + warp_m * 128 + i * 16 + lq * 4 + r;
                    const int col = n0 + warp_n * 64 + j * 16 + lr;
                    Of32[(size_t)row * 1024 + col] = acc[i][j][r];
                }
    }
}

// ---------------------------------------------------------------------------
// KV + k_sum partials from TRANSPOSED K/V (unchanged — verified R6)
// ---------------------------------------------------------------------------
#define KV_SPLIT 8
__global__ __launch_bounds__(256)
void kv_gemm(const __hip_bfloat16* __restrict__ KB,
             const __hip_bfloat16* __restrict__ VB,
             float* __restrict__ KVp)
{
    __shared__ float sRed[65 * 66];

    const int bh = blockIdx.x;
    const int sp = blockIdx.y;
    const int t  = threadIdx.x;
    const int lane = t & 63;
    const int wv = t >> 6;
    const int lr = lane & 15;
    const int lq = lane >> 4;

    const __hip_bfloat16* kbase = KB + (size_t)bh * 64 * 4096;
    const __hip_bfloat16* vbase = VB + (size_t)bh * 64 * 4096;
    const int k0w = sp * 512 + wv * 128 + lq * 8;

    f32x4 acc[4][4];
    f32x4 ksacc[4];
    #pragma unroll
    for (int i = 0; i < 4; i++) {
        ksacc[i] = (f32x4){0.f, 0.f, 0.f, 0.f};
        #pragma unroll
        for (int j = 0; j < 4; j++)
            acc[i][j] = (f32x4){0.f, 0.f, 0.f, 0.f};
    }

    bf16x8 ones;
    #pragma unroll
    for (int j = 0; j < 8; j++) ones[j] = (__bf16)1.0f;

    #pragma unroll
    for (int c = 0; c < 4; ++c) {
        const int k0 = k0w + c * 32;
        bf16x8 ak[4], bv[4];
        #pragma unroll
        for (int i = 0; i < 4; ++i) {
            ak[i] = *(const bf16x8*)(kbase + (size_t)(i * 16 + lr) * 4096 + k0);
            bv[i] = *(const bf16x8*)(vbase + (size_t)(i * 16 + lr) * 4096 + k0);
        }
        #pragma unroll
        for (int i = 0; i < 4; ++i) {
            #pragma unroll
            for (int j = 0; j < 4; ++j)
                acc[i][j] = __builtin_amdgcn_mfma_f32_16x16x32_bf16(ak[i], bv[j], acc[i][j], 0, 0, 0);
            ksacc[i] = __builtin_amdgcn_mfma_f32_16x16x32_bf16(ak[i], ones, ksacc[i], 0, 0, 0);
        }
    }

    for (int w = 0; w < 4; w++) {
        if (wv == w) {
            #pragma unroll
            for (int i = 0; i < 4; i++) {
                #pragma unroll
                for (int j = 0; j < 4; j++) {
                    float* p = &sRed[(j * 16 + lr) * 66 + i * 16 + lq * 4];
                    if (w == 0) {
                        #pragma unroll
                        for (int r = 0; r < 4; r++) p[r] = acc[i][j][r];
                    } else {
                        #pragma unroll
                        for (int r = 0; r < 4; r++) p[r] += acc[i][j][r];
                    }
                }
                if (lr == 0) {
                    float* p = &sRed[64 * 66 + i * 16 + lq * 4];
                    if (w == 0) {
                        #pragma unroll
                        for (int r = 0; r < 4; r++) p[r] = ksacc[i][r];
                    } else {
                        #pragma unroll
                        for (int r = 0; r < 4; r++) p[r] += ksacc[i][r];
                    }
                }
            }
        }
        __syncthreads();
    }

    float* outp = KVp + (size_t)(sp * 64 + bh) * (65 * 64);
    #pragma unroll
    for (int i = 0; i < 17; i++) {
        int idx = i * 256 + t;
        if (idx < 65 * 64) {
            int e = idx >> 6, d = idx & 63;
            outp[idx] = sRed[e * 66 + d];
        }
    }
}

// ---------------------------------------------------------------------------
// Reduce partials -> KVt + KS. R8: widened 64 -> 256 blocks (grid 64x4);
// previous version left 192 CUs idle.
// ---------------------------------------------------------------------------
__global__ __launch_bounds__(256)
void kv_reduce(const float* __restrict__ KVp,
               __hip_bfloat16* __restrict__ KVt,
               float* __restrict__ KS)
{
    const int bh = blockIdx.x;
    const int q  = blockIdx.y;     // 0..3
    const int t  = threadIdx.x;
    #pragma unroll
    for (int i = 0; i < 4; i++) {
        int idx = q * 1024 + i * 256 + t;
        float s = 0.f;
        #pragma unroll
        for (int sp = 0; sp < KV_SPLIT; sp++)
            s += KVp[((size_t)(sp * 64 + bh) * 65) * 64 + idx];
        KVt[(size_t)bh * 4096 + idx] = __float2bfloat16(s);
    }
    if (q == 0 && t < 64) {
        float s = 0.f;
        #pragma unroll
        for (int sp = 0; sp < KV_SPLIT; sp++)
            s += KVp[((size_t)(sp * 64 + bh) * 65 + 64) * 64 + t];
        KS[bh * 64 + t] = s;
    }
}

// ---------------------------------------------------------------------------
// MFMA attention apply (unchanged — verified)
// ---------------------------------------------------------------------------
__global__ __launch_bounds__(256)
void attn_mfma(const __hip_bfloat16* __restrict__ Q,
               const __hip_bfloat16* __restrict__ KVt,
               const float* __restrict__ KS,
               __hip_bfloat16* __restrict__ O)
{
    const int bh = blockIdx.x;
    const int b  = bh >> 4;
    const int h  = bh & 15;
    const int s0 = blockIdx.y * 128;
    const int t  = threadIdx.x;
    const int lane = t & 63;
    const int wv = t >> 6;

    __shared__ __align__(16) __hip_bfloat16 sQ[128][72];
    __shared__ __align__(16) __hip_bfloat16 sKVt[64][72];
    __shared__ float sKS[64];
    __shared__ float sZ[128];

    {
        const float4* kvp = (const float4*)(KVt + (size_t)bh * 4096);
        #pragma unroll
        for (int i = 0; i < 2; i++) {
            int c = i * 256 + t;
            *(float4*)(&sKVt[c >> 3][(c & 7) * 8]) = kvp[c];
        }
        if (t < 64) sKS[t] = KS[bh * 64 + t];
    }
    {
        const __hip_bfloat16* qp = Q + ((size_t)b * SS + s0) * DD + h * HD;
        int r  = t >> 1;
        int c0 = (t & 1) * 32;
        #pragma unroll
        for (int i = 0; i < 32; i += 8)
            *(float4*)(&sQ[r][c0 + i]) = *(const float4*)(qp + (size_t)r * DD + c0 + i);
    }
    __syncthreads();

    if (t < 128) {
        float z = 0.f;
        #pragma unroll
        for (int d8 = 0; d8 < 64; d8 += 8) {
            bf16x8 qv = *(const bf16x8*)(&sQ[t][d8]);
            #pragma unroll
            for (int j = 0; j < 8; j++) z += (float)qv[j] * sKS[d8 + j];
        }
        sZ[t] = 1.f / (z + 1e-6f);
    }

    const int lr = lane & 15;
    const int lq = lane >> 4;
    f32x4 acc[2][4];
    #pragma unroll
    for (int i = 0; i < 2; i++)
        #pragma unroll
        for (int j = 0; j < 4; j++)
            acc[i][j] = (f32x4){0.f, 0.f, 0.f, 0.f};

    bf16x8 af[2][2], bfv[4][2];
    #pragma unroll
    for (int ks = 0; ks < 2; ks++) {
        #pragma unroll
        for (int i = 0; i < 2; i++)
            af[i][ks] = *(const bf16x8*)(&sQ[wv * 32 + i * 16 + lr][lq * 8 + ks * 32]);
        #pragma unroll
        for (int j = 0; j < 4; j++)
            bfv[j][ks] = *(const bf16x8*)(&sKVt[j * 16 + lr][lq * 8 + ks * 32]);
    }
    #pragma unroll
    for (int i = 0; i < 2; i++)
        #pragma unroll
        for (int j = 0; j < 4; j++) {
            acc[i][j] = __builtin_amdgcn_mfma_f32_16x16x32_bf16(af[i][0], bfv[j][0], acc[i][j], 0, 0, 0);
            acc[i][j] = __builtin_amdgcn_mfma_f32_16x16x32_bf16(af[i][1], bfv[j][1], acc[i][j], 0, 0, 0);
        }
    __syncthreads();

    __hip_bfloat16* op = O + ((size_t)b * SS + s0) * DD + h * HD;
    #pragma unroll
    for (int i = 0; i < 2; i++)
        #pragma unroll
        for (int j = 0; j < 4; j++)
            #pragma unroll
            for (int r = 0; r < 4; r++) {
                int row = wv * 32 + i * 16 + lq * 4 + r;
                int col = j * 16 + lr;
                op[(size_t)row * DD + col] = __float2bfloat16(acc[i][j][r] * sZ[row]);
            }
}

// ---------------------------------------------------------------------------
// launch
// ---------------------------------------------------------------------------
extern "C" void kernel_launch(void* const* d_in, const int* in_sizes, int n_in,
                              void* d_out, int out_size, void* d_ws, size_t ws_size,
                              hipStream_t stream) {
    const float* x  = (const float*)d_in[0];
    const float* Wq = (const float*)d_in[1];
    const float* Wk = (const float*)d_in[2];
    const float* Wv = (const float*)d_in[3];
    const float* Wo = (const float*)d_in[4];
    float* out = (float*)d_out;

    char* ws = (char*)d_ws;
    const size_t XB_BYTES = (size_t)MM * KK * 2;   // 32MB
    const size_t WB_BYTES = (size_t)NN * KK * 2;   // 2MB
    __hip_bfloat16* xb  = (__hip_bfloat16*)(ws);
    __hip_bfloat16* wqb = (__hip_bfloat16*)(ws + XB_BYTES);
    __hip_bfloat16* wob = (__hip_bfloat16*)(ws + XB_BYTES + 3 * WB_BYTES);
    __hip_bfloat16* qb  = (__hip_bfloat16*)(ws + XB_BYTES + 4 * WB_BYTES);
    __hip_bfloat16* kb  = (__hip_bfloat16*)(ws + 2 * XB_BYTES + 4 * WB_BYTES);  // K^T [bh][d][s]
    __hip_bfloat16* vb  = (__hip_bfloat16*)(ws + 3 * XB_BYTES + 4 * WB_BYTES);  // V^T [bh][d][s]
    __hip_bfloat16* KVt = (__hip_bfloat16*)(ws + 4 * XB_BYTES + 4 * WB_BYTES);          // 512KB
    float*          KS  = (float*)(ws + 4 * XB_BYTES + 4 * WB_BYTES + 524288);          // 16KB
    // KV partials (8.3MB f32) overlay xb (dead after QKV GEMM; attn writes
    // ab=xb only after kv_reduce). Stream-ordered, safe.
    float* KVp = (float*)(ws);
    __hip_bfloat16* ab = xb;

    // 1. convert ALL inputs to bf16 in one launch (xb | wq|wk|wv|wo contiguous)
    cvt_all<<<(MM * KK + 4 * NN * KK) / 1024, 256, 0, stream>>>(x, Wq, Wk, Wv, Wo, xb);

    // 2. fused QKV projection: [16384,1024] @ [3072,1024]^T.
    //    Q -> qb row-major (+elu); K,V -> kb,vb TRANSPOSED [bh][d][s].
    gemm256<0><<<768, 512, 0, stream>>>(xb, wqb, qb, nullptr);

    // 3. KV + k_sum partials (B^T GEMM on transposed K/V), then reduce (wide)
    kv_gemm<<<dim3(BB * HH, KV_SPLIT), 256, 0, stream>>>(kb, vb, KVp);
    kv_reduce<<<dim3(BB * HH, 4), 256, 0, stream>>>(KVp, KVt, KS);

    // 4. attention output (normalized), bf16, MFMA
    attn_mfma<<<dim3(BB * HH, SS / 128), 256, 0, stream>>>(qb, KVt, KS, ab);

    // 5. final projection -> fp32 d_out
    gemm256<1><<<256, 512, 0, stream>>>(ab, wob, nullptr, out);
}